// Round 3
// baseline (455.430 us; speedup 1.0000x reference)
//
#include <hip/hip_runtime.h>
#include <hip/hip_bf16.h>

#define N_NODES 20000
#define N_EDGES 320000
#define DIM 128
#define HEADS 3
#define LAYERS 3
#define NGRAPH 64
#define NEG_SLOPE 0.2f
#define NODE_BLOCKS ((N_NODES + 63) / 64)   // 313

typedef const __hip_bfloat16* bfp;
typedef __hip_bfloat16 bf16;
typedef short v8s __attribute__((ext_vector_type(8)));
typedef float v4f __attribute__((ext_vector_type(4)));

#define GLD_LDS(gp, lp) \
    __builtin_amdgcn_global_load_lds( \
        (const __attribute__((address_space(1))) void*)(gp), \
        (__attribute__((address_space(3))) void*)(lp), 16, 0, 0)

__device__ __forceinline__ float b2f(unsigned short u) {
    return __uint_as_float(((unsigned)u) << 16);
}
__device__ __forceinline__ float lo2f(unsigned u) { return __uint_as_float(u << 16); }
__device__ __forceinline__ float hi2f(unsigned u) { return __uint_as_float(u & 0xffff0000u); }
__device__ __forceinline__ float leaky(float z) {
    return z >= 0.f ? z : NEG_SLOPE * z;
}
__device__ __forceinline__ unsigned packbf(float a, float b) {
    bf16 x = __float2bfloat16(a), y = __float2bfloat16(b);
    return (unsigned)*(unsigned short*)&x | ((unsigned)*(unsigned short*)&y << 16);
}
__device__ __forceinline__ unsigned short f2bfbits(float v) {
    bf16 x = __float2bfloat16(v);
    return *(unsigned short*)&x;
}

// XOR-swizzled 32-col chunk staging (validated R13)
__device__ __forceinline__ void stage_swz(const short* base, int t0, int K,
                                          int k0, short* lds, int gidx) {
    int row = gidx >> 2, pos = gidx & 3;
    int kch = pos ^ ((row >> 1) & 3);
    GLD_LDS(base + (size_t)(t0 + row) * K + k0 + kch * 8, lds + gidx * 8);
}
__device__ __forceinline__ v8s fragx(const short* lds, int R, int q) {
    int g = R * 4 + (q ^ ((R >> 1) & 3));
    return *(const v8s*)(lds + g * 8);
}

// Full-panel staging: A 64x128 = 1024 granules; B 128x128 = 2048 granules.
__device__ __forceinline__ void stage_panelA(const short* base, int t0, int K,
                                             int k0, short* lds, int tid) {
#pragma unroll
    for (int j = 0; j < 4; ++j) {
        int g = j * 256 + tid;
        stage_swz(base, t0, K, k0 + (g >> 8) * 32, lds + (g >> 8) * 2048, g & 255);
    }
}
__device__ __forceinline__ void stage_panelB(const short* base, int t0, int K,
                                             int k0, short* lds, int tid) {
#pragma unroll
    for (int j = 0; j < 8; ++j) {
        int g = j * 256 + tid;
        stage_swz(base, t0, K, k0 + (g >> 9) * 32, lds + (g >> 9) * 4096, g & 511);
    }
}

// ---------------- init: zero workspace region + dtype detect ----------------
__global__ void init_kernel(unsigned* __restrict__ z, int nzd,
                            const unsigned short* __restrict__ probe,
                            int* __restrict__ dflag) {
    int gid = blockIdx.x * 256 + threadIdx.x;
    for (int i = gid; i < nzd; i += gridDim.x * 256) z[i] = 0u;
    if (blockIdx.x == 0) {
        int c = 0;
#pragma unroll
        for (int j = 0; j < 64; ++j) {
            unsigned short u = probe[threadIdx.x * 64 + j];
            c += (((u >> 7) & 0xFF) >= 140) ? 1 : 0;
        }
        for (int o = 32; o > 0; o >>= 1) c += __shfl_down(c, o);
        __shared__ int r[4];
        if ((threadIdx.x & 63) == 0) r[threadIdx.x >> 6] = c;
        __syncthreads();
        if (threadIdx.x == 0) *dflag = r[0] + r[1] + r[2] + r[3];
    }
}

// ---------------- fused cvt (all float inputs -> bf16) + edge histogram -----
#define NCVT 9
struct CvtArgs {
    const void* src[NCVT];
    bf16* dst[NCVT];
    int n4[NCVT];
    int n[NCVT];
};
__global__ void cvtcount_kernel(CvtArgs args, const int* __restrict__ flag,
                                const int* __restrict__ dst, int* __restrict__ deg,
                                int cvtBlocks) {
    if ((int)blockIdx.x >= cvtBlocks) {
        int e = (blockIdx.x - cvtBlocks) * 256 + threadIdx.x;
        if (e < N_EDGES) atomicAdd(&deg[dst[e]], 1);
        return;
    }
    int i = blockIdx.x * 256 + threadIdx.x;
    int f = (*flag) > 8;
#pragma unroll
    for (int s = 0; s < NCVT; ++s) {
        int ns4 = args.n4[s];
        if (i < ns4) {
            int ns = args.n[s];
            int base = i * 4;
            bf16* dstp = args.dst[s];
            if (f) {
                const float* sp = (const float*)args.src[s];
                if (base + 3 < ns) {
                    float4 v = *(const float4*)(sp + base);
                    ushort4 pk = { f2bfbits(v.x), f2bfbits(v.y),
                                   f2bfbits(v.z), f2bfbits(v.w) };
                    *(ushort4*)(dstp + base) = pk;
                } else {
                    for (int j = 0; j < 4 && base + j < ns; ++j)
                        dstp[base + j] = __float2bfloat16(sp[base + j]);
                }
            } else {
                const bf16* sp = (const bf16*)args.src[s];
                if (base + 3 < ns) {
                    *(ushort4*)(dstp + base) = *(const ushort4*)(sp + base);
                } else {
                    for (int j = 0; j < 4 && base + j < ns; ++j)
                        dstp[base + j] = sp[base + j];
                }
            }
            return;
        }
        i -= ns4;
    }
}

// ---------------- fused: deg scan (shfl block-scan) + gptr binary search ----
__global__ void scan_gptr_kernel(const int* __restrict__ cnt, int* __restrict__ ptr,
                                 const int* __restrict__ gid, int* __restrict__ gptr) {
    int tid = threadIdx.x;
    if (tid <= NGRAPH) {
        int lo = 0, hi = N_NODES;
        while (lo < hi) {
            int mid = (lo + hi) >> 1;
            if (gid[mid] < tid) lo = mid + 1; else hi = mid;
        }
        gptr[tid] = lo;
    }
    const int chunk = (N_NODES + 255) / 256;
    int b = tid * chunk, e = min(b + chunk, N_NODES);
    int loc = 0;
    for (int i = b; i < e; ++i) loc += cnt[i];
    int lane = tid & 63, wv = tid >> 6;
    int v = loc;
#pragma unroll
    for (int o = 1; o < 64; o <<= 1) {
        int t = __shfl_up(v, o);
        if (lane >= o) v += t;
    }
    __shared__ int wsum[4];
    if (lane == 63) wsum[wv] = v;
    __syncthreads();
    int wo = 0;
    for (int j = 0; j < wv; ++j) wo += wsum[j];
    int run = wo + v - loc;
    if (tid == 255) ptr[N_NODES] = wsum[0] + wsum[1] + wsum[2] + wsum[3];
    for (int i = b; i < e; ++i) { ptr[i] = run; run += cnt[i]; }
}

__global__ void sentinel_kernel(bf16* out, int n) {
    int i = blockIdx.x * 256 + threadIdx.x;
    if (i < n) out[i] = __float2bfloat16(2.0f);
}

// ---------------- prep: vcat = fcW^T @ a  and  Mcat = tw_h @ fcW_h ----------
__global__ __launch_bounds__(256) void prep_kernel(
    const bf16* __restrict__ cfc, const bf16* __restrict__ cans,
    const bf16* __restrict__ cand, const bf16* __restrict__ ctw,
    bf16* __restrict__ mcat, float* __restrict__ vcat)
{
    const int l = blockIdx.x / 25;
    const int b = blockIdx.x % 25;
    const bf16* fc = cfc + (size_t)l * 384 * 128;
    if (b < 24) {
        const int h = b >> 3, kc = b & 7;
        const bf16* tw = ctw + (size_t)l * 128 * 384;
        bf16* mc = mcat + (size_t)l * 128 * 384;
        const int d = threadIdx.x & 127;
        const int kh = threadIdx.x >> 7;
        const int k0 = kc * 16 + kh * 8;
        float acc[8] = {0.f, 0.f, 0.f, 0.f, 0.f, 0.f, 0.f, 0.f};
        for (int j = 0; j < 128; ++j) {
            float w = __bfloat162float(tw[(size_t)d * 384 + h * 128 + j]);
            v8s fv = *(const v8s*)(fc + (size_t)(h * 128 + j) * 128 + k0);
#pragma unroll
            for (int i = 0; i < 8; ++i)
                acc[i] += w * b2f((unsigned short)fv[i]);
        }
        v8s ov;
#pragma unroll
        for (int i = 0; i < 8; ++i) ov[i] = (short)f2bfbits(acc[i]);
        *(v8s*)(mc + (size_t)d * 384 + h * 128 + k0) = ov;
    } else {
        const int k = threadIdx.x & 127;
        const int grp = threadIdx.x >> 7;   // 0 = ns, 1 = nd
        const bf16* av = (grp ? cand : cans) + (size_t)l * 384;
        float a0 = 0.f, a1 = 0.f, a2 = 0.f;
        for (int j = 0; j < 128; ++j) {
            a0 += __bfloat162float(av[j])       * __bfloat162float(fc[(size_t)j * 128 + k]);
            a1 += __bfloat162float(av[128 + j]) * __bfloat162float(fc[(size_t)(128 + j) * 128 + k]);
            a2 += __bfloat162float(av[256 + j]) * __bfloat162float(fc[(size_t)(256 + j) * 128 + k]);
        }
        float* vc = vcat + (size_t)l * 6 * 128;
        vc[(grp * 3 + 0) * 128 + k] = a0;
        vc[(grp * 3 + 1) * 128 + k] = a1;
        vc[(grp * 3 + 2) * 128 + k] = a2;
    }
}

// ---------------- MFMA GEMM (MODE 2 gate path only now) ---------------------
template <int MODE, int KSUP>
__global__ __launch_bounds__(256) void gemm_mfma(
    const bf16* __restrict__ A, const bf16* __restrict__ B,
    bf16* __restrict__ C, int M, int N,
    const bf16* __restrict__ bias, const bf16* __restrict__ resid,
    int do_relu, const bf16* __restrict__ p2w, float* __restrict__ gpart)
{
    __shared__ short lsA[8192];
    __shared__ short lsB[16384];
    const int tid  = threadIdx.x;
    const int wave = tid >> 6;
    const int lane = tid & 63;
    const int quad = lane >> 4;
    const int r16  = lane & 15;
    const int m0 = blockIdx.x * 64;
    const int n0 = blockIdx.y * 128;
    const int K = KSUP * 128;
    const short* As = (const short*)A;
    const short* Bs = (const short*)B;

    v4f acc[8];
#pragma unroll
    for (int t = 0; t < 8; ++t) acc[t] = (v4f){0.f, 0.f, 0.f, 0.f};

#pragma unroll
    for (int ks = 0; ks < KSUP; ++ks) {
        const int k0 = ks * 128;
        stage_panelA(As, m0, K, k0, lsA, tid);
        stage_panelB(Bs, n0, K, k0, lsB, tid);
        __syncthreads();
#pragma unroll
        for (int c = 0; c < 4; ++c) {
            v8s a = fragx(lsA + c * 2048, wave * 16 + r16, quad);
#pragma unroll
            for (int t = 0; t < 8; ++t) {
                v8s b = fragx(lsB + c * 4096, t * 16 + r16, quad);
                acc[t] = __builtin_amdgcn_mfma_f32_16x16x32_bf16(a, b, acc[t], 0, 0, 0);
            }
        }
        if (ks + 1 < KSUP) __syncthreads();
    }

    const int mb = m0 + wave * 16;

    if (MODE == 2) {
        float pwv[8], bbv[8];
#pragma unroll
        for (int t = 0; t < 8; ++t) {
            int n = n0 + t * 16 + r16;
            pwv[t] = __bfloat162float(p2w[n]);
            bbv[t] = __bfloat162float(bias[n]);
        }
#pragma unroll
        for (int reg = 0; reg < 4; ++reg) {
            float g = 0.f;
#pragma unroll
            for (int t = 0; t < 8; ++t)
                g += fmaxf(acc[t][reg] + bbv[t], 0.f) * pwv[t];
#pragma unroll
            for (int o = 1; o < 16; o <<= 1) g += __shfl_xor(g, o);
            int m = mb + quad * 4 + reg;
            if (r16 == 0 && m < M) gpart[(size_t)blockIdx.y * N_NODES + m] = g;
        }
        return;
    }

#pragma unroll
    for (int t = 0; t < 8; ++t) {
        const int n = n0 + t * 16 + r16;
        float bb = bias ? __bfloat162float(bias[n]) : 0.f;
#pragma unroll
        for (int reg = 0; reg < 4; ++reg) {
            const int m = mb + quad * 4 + reg;
            if (m >= M) continue;
            float v = acc[t][reg];
            if (bias) {
                v += bb;
                if (do_relu) v = fmaxf(v, 0.f);
            }
            if (resid) v += __bfloat162float(resid[(size_t)m * N + n]);
            C[(size_t)m * N + n] = __float2bfloat16(v);
        }
    }
}

// ---------------- score block: s_all[n][{0..2,4..6}] = feat[n]·vcat[c] ------
__device__ __forceinline__ void score_block(
    const unsigned* __restrict__ featdw, const float* __restrict__ vc,
    float* __restrict__ s_all, int blk, int tid)
{
    const int wv = tid >> 6, lane = tid & 63;
    float2 vv0 = *(const float2*)(vc + 0 * 128 + lane * 2);
    float2 vv1 = *(const float2*)(vc + 1 * 128 + lane * 2);
    float2 vv2 = *(const float2*)(vc + 2 * 128 + lane * 2);
    float2 vv3 = *(const float2*)(vc + 3 * 128 + lane * 2);
    float2 vv4 = *(const float2*)(vc + 4 * 128 + lane * 2);
    float2 vv5 = *(const float2*)(vc + 5 * 128 + lane * 2);
    const int nbase = blk * 64 + wv * 16;
#pragma unroll 1
    for (int t = 0; t < 16; ++t) {
        const int n = nbase + t;
        if (n >= N_NODES) return;
        unsigned u = featdw[(size_t)n * 64 + lane];
        float lo = lo2f(u), hi = hi2f(u);
        float p0 = lo * vv0.x + hi * vv0.y;
        float p1 = lo * vv1.x + hi * vv1.y;
        float p2 = lo * vv2.x + hi * vv2.y;
        float p3 = lo * vv3.x + hi * vv3.y;
        float p4 = lo * vv4.x + hi * vv4.y;
        float p5 = lo * vv5.x + hi * vv5.y;
#pragma unroll
        for (int o = 1; o < 64; o <<= 1) {
            p0 += __shfl_xor(p0, o); p1 += __shfl_xor(p1, o);
            p2 += __shfl_xor(p2, o); p3 += __shfl_xor(p3, o);
            p4 += __shfl_xor(p4, o); p5 += __shfl_xor(p5, o);
        }
        float outv = p0;
        outv = (lane == 1) ? p1 : outv;
        outv = (lane == 2) ? p2 : outv;
        outv = (lane == 4) ? p3 : outv;
        outv = (lane == 5) ? p4 : outv;
        outv = (lane == 6) ? p5 : outv;
        if (lane < 7 && lane != 3)
            s_all[(size_t)n * 8 + lane] = outv;
    }
}

// ---------------- merged: pool(d-1) | fill(d==0) | score(d==0) --------------
__global__ __launch_bounds__(256) void poolfc_kernel(
    const bf16* __restrict__ pfeat, const float* __restrict__ gp,
    const int* __restrict__ gptr, float* __restrict__ out_acc,
    const float* __restrict__ vc, float* __restrict__ s_all,
    const int* __restrict__ src, const int* __restrict__ dst,
    const int* __restrict__ rp, int* __restrict__ cursor,
    int* __restrict__ esrc,
    int poolBlocks, int fillBlocks)
{
    __shared__ float red[4];
    const int tid = threadIdx.x;
    if ((int)blockIdx.x < poolBlocks) {
        const int g = blockIdx.x >> 3;
        const int chunk = blockIdx.x & 7;
        const int beg = gptr[g], end = gptr[g + 1];
        if (beg >= end) return;
        float m = -1e30f;
        for (int i = beg + tid; i < end; i += 256)
            m = fmaxf(m, gp[i] + gp[N_NODES + i]);
#pragma unroll
        for (int o = 32; o > 0; o >>= 1) m = fmaxf(m, __shfl_xor(m, o));
        if ((tid & 63) == 0) red[tid >> 6] = m;
        __syncthreads();
        m = fmaxf(fmaxf(red[0], red[1]), fmaxf(red[2], red[3]));
        __syncthreads();
        float s = 0.f;
        for (int i = beg + tid; i < end; i += 256)
            s += __expf(gp[i] + gp[N_NODES + i] - m);
#pragma unroll
        for (int o = 32; o > 0; o >>= 1) s += __shfl_xor(s, o);
        if ((tid & 63) == 0) red[tid >> 6] = s;
        __syncthreads();
        float inv = 1.f / (red[0] + red[1] + red[2] + red[3]);
        const int p = tid >> 7;
        const int c = tid & 127;
        float acc = 0.f;
        for (int i = beg + chunk * 2 + p; i < end; i += 16) {
            float w = __expf(gp[i] + gp[N_NODES + i] - m);
            acc += w * __bfloat162float(pfeat[(size_t)i * DIM + c]);
        }
        acc *= inv;
        atomicAdd(&out_acc[g * DIM + c], acc);
        return;
    }
    if ((int)blockIdx.x < poolBlocks + fillBlocks) {
        int e = (blockIdx.x - poolBlocks) * 256 + tid;
        if (e < N_EDGES) {
            int d = dst[e];
            int pos = rp[d] + atomicAdd(&cursor[d], 1);
            esrc[pos] = src[e];
        }
        return;
    }
    const int blk = blockIdx.x - poolBlocks - fillBlocks;
    score_block((const unsigned*)pfeat, vc, s_all, blk, tid);
}

// ---------------- fused agg + trans-GEMM + next-layer scores ----------------
// Block = 64 dst nodes. Phase 1: each wave aggregates 16 nodes' weighted-feat
// rows (384 wide, 3 heads x same 256B gather) straight into a 64x384 LDS
// A-tile, written pre-swizzled in fragx layout. Phase 2: MFMA GEMM vs Mcat
// (K=384, staged 16KB/step). Epilogue: bias+relu+resid+C-write and the six
// folded score dots for layer d+1 (s_next; double-buffered vs s_cur to avoid
// the cross-block read/write race).
__global__ __launch_bounds__(256) void aggemm_kernel(
    const unsigned* __restrict__ featdw, const int* __restrict__ rp,
    const int* __restrict__ esrc, const float* __restrict__ s_cur,
    float* __restrict__ s_next, const bf16* __restrict__ Bmat,
    const bf16* __restrict__ bias, bf16* __restrict__ C,
    const float* __restrict__ vc_next, int do_relu)
{
    __shared__ short lsAgg[24576];   // 48KB: 64 rows x 384 k, swizzled chunks
    __shared__ short lsB[8192];      // 16KB: B k-step buffer (pv area in ph.1)
    float4* pv = (float4*)lsB;
    unsigned* lsAggDw = (unsigned*)lsAgg;
    const int tid = threadIdx.x;
    const int wv = tid >> 6, lane = tid & 63;
    const int quad = lane >> 4, r16 = lane & 15;
    const int m0 = blockIdx.x * 64;

    // ---- phase 1: aggregate ----
#pragma unroll 1
    for (int t = 0; t < 16; ++t) {
        const int row = wv * 16 + t;
        const int node = m0 + row;
        float a00 = 0.f, a01 = 0.f, a10 = 0.f, a11 = 0.f, a20 = 0.f, a21 = 0.f;
        float i0 = 0.f, i1 = 0.f, i2 = 0.f;
        if (node < N_NODES) {
            const int beg = rp[node], end = rp[node + 1];
            const int cnt = end - beg;
            if (cnt > 0) {
                const float nd0 = s_cur[(size_t)node * 8 + 4];
                const float nd1 = s_cur[(size_t)node * 8 + 5];
                const float nd2 = s_cur[(size_t)node * 8 + 6];
                float sl0 = 0.f, sl1 = 0.f, sl2 = 0.f;
                for (int c0 = 0; c0 < cnt; c0 += 64) {
                    const int ce = min(64, cnt - c0);
                    if (lane < ce) {
                        int s = esrc[beg + c0 + lane];
                        float4 q = *(const float4*)(s_cur + (size_t)s * 8);
                        float4 r;
                        r.x = __expf(leaky(q.x + nd0));
                        r.y = __expf(leaky(q.y + nd1));
                        r.z = __expf(leaky(q.z + nd2));
                        r.w = __int_as_float(s);
                        sl0 += r.x; sl1 += r.y; sl2 += r.z;
                        pv[wv * 64 + lane] = r;
                    }
#pragma unroll 8
                    for (int j = 0; j < ce; ++j) {
                        float4 e = pv[wv * 64 + j];        // broadcast b128
                        int s = __float_as_int(e.w);
                        unsigned u = featdw[(size_t)s * 64 + lane]; // 256B/wave
                        float lo = lo2f(u), hi = hi2f(u);
                        a00 += e.x * lo; a01 += e.x * hi;
                        a10 += e.y * lo; a11 += e.y * hi;
                        a20 += e.z * lo; a21 += e.z * hi;
                    }
                }
#pragma unroll
                for (int o = 1; o < 64; o <<= 1) {
                    sl0 += __shfl_xor(sl0, o);
                    sl1 += __shfl_xor(sl1, o);
                    sl2 += __shfl_xor(sl2, o);
                }
                i0 = 1.f / sl0; i1 = 1.f / sl1; i2 = 1.f / sl2;
            }
        }
        // write swizzled row (fragx layout: chunk kc, granule row*4+(q^s))
#pragma unroll
        for (int c = 0; c < 3; ++c) {
            float va = (c == 0) ? a00 * i0 : (c == 1) ? a10 * i1 : a20 * i2;
            float vb = (c == 0) ? a01 * i0 : (c == 1) ? a11 * i1 : a21 * i2;
            int d_idx = c * 64 + lane;
            int kc = d_idx >> 4, w = d_idx & 15;
            int q = w >> 2, pos = w & 3;
            lsAggDw[kc * 1024 + (row * 4 + (q ^ ((row >> 1) & 3))) * 4 + pos] =
                packbf(va, vb);
        }
    }
    __syncthreads();

    // ---- phase 2: GEMM 64x384 @ 384x128 ----
    const short* Bs = (const short*)Bmat;
    v4f acc[8];
#pragma unroll
    for (int t = 0; t < 8; ++t) acc[t] = (v4f){0.f, 0.f, 0.f, 0.f};
#pragma unroll 1
    for (int kk = 0; kk < 6; ++kk) {
        if (kk) __syncthreads();
#pragma unroll
        for (int j = 0; j < 4; ++j) {
            int g = j * 256 + tid;
            int c = g >> 9, gi = g & 511;
            stage_swz(Bs, 0, 384, kk * 64 + c * 32, lsB + c * 4096, gi);
        }
        __syncthreads();
#pragma unroll
        for (int c = 0; c < 2; ++c) {
            v8s a = fragx(lsAgg + (kk * 2 + c) * 2048, wv * 16 + r16, quad);
#pragma unroll
            for (int t = 0; t < 8; ++t) {
                v8s b = fragx(lsB + c * 4096, t * 16 + r16, quad);
                acc[t] = __builtin_amdgcn_mfma_f32_16x16x32_bf16(a, b, acc[t], 0, 0, 0);
            }
        }
    }

    // ---- epilogue ----
    const int mb = m0 + wv * 16;
    float bbv[8];
#pragma unroll
    for (int t = 0; t < 8; ++t) bbv[t] = __bfloat162float(bias[t * 16 + r16]);
    float sc0[4], sc1[4], sc2[4], sc3[4], sc4[4], sc5[4];
#pragma unroll
    for (int reg = 0; reg < 4; ++reg) {
        sc0[reg] = 0.f; sc1[reg] = 0.f; sc2[reg] = 0.f;
        sc3[reg] = 0.f; sc4[reg] = 0.f; sc5[reg] = 0.f;
    }
#pragma unroll
    for (int t = 0; t < 8; ++t) {
        const int n = t * 16 + r16;
        float v0 = vc_next ? vc_next[0 * 128 + n] : 0.f;
        float v1 = vc_next ? vc_next[1 * 128 + n] : 0.f;
        float v2 = vc_next ? vc_next[2 * 128 + n] : 0.f;
        float v3 = vc_next ? vc_next[3 * 128 + n] : 0.f;
        float v4 = vc_next ? vc_next[4 * 128 + n] : 0.f;
        float v5 = vc_next ? vc_next[5 * 128 + n] : 0.f;
#pragma unroll
        for (int reg = 0; reg < 4; ++reg) {
            const int m = mb + quad * 4 + reg;
            if (m >= N_NODES) continue;
            float v = acc[t][reg] + bbv[t];
            if (do_relu) v = fmaxf(v, 0.f);
            v += __bfloat162float(((const bf16*)featdw)[(size_t)m * 128 + n]);
            C[(size_t)m * 128 + n] = __float2bfloat16(v);
            sc0[reg] += v * v0; sc1[reg] += v * v1; sc2[reg] += v * v2;
            sc3[reg] += v * v3; sc4[reg] += v * v4; sc5[reg] += v * v5;
        }
    }
    if (vc_next) {
#pragma unroll
        for (int reg = 0; reg < 4; ++reg) {
#pragma unroll
            for (int o = 1; o < 16; o <<= 1) {
                sc0[reg] += __shfl_xor(sc0[reg], o);
                sc1[reg] += __shfl_xor(sc1[reg], o);
                sc2[reg] += __shfl_xor(sc2[reg], o);
                sc3[reg] += __shfl_xor(sc3[reg], o);
                sc4[reg] += __shfl_xor(sc4[reg], o);
                sc5[reg] += __shfl_xor(sc5[reg], o);
            }
            const int m = mb + quad * 4 + reg;
            if (r16 == 0 && m < N_NODES) {
                s_next[(size_t)m * 8 + 0] = sc0[reg];
                s_next[(size_t)m * 8 + 1] = sc1[reg];
                s_next[(size_t)m * 8 + 2] = sc2[reg];
                s_next[(size_t)m * 8 + 4] = sc3[reg];
                s_next[(size_t)m * 8 + 5] = sc4[reg];
                s_next[(size_t)m * 8 + 6] = sc5[reg];
            }
        }
    }
}

// ---------------- standalone final pool (no fence — R20 errata) -------------
__global__ void __launch_bounds__(256) pool_acc(
    const bf16* __restrict__ feat, const float* __restrict__ gp,
    const int* __restrict__ gptr, float* __restrict__ out_acc)
{
    const int g = blockIdx.x;
    const int chunk = blockIdx.y;
    const int tid = threadIdx.x;
    const int beg = gptr[g], end = gptr[g + 1];
    if (beg >= end) return;
    __shared__ float red[4];
    float m = -1e30f;
    for (int i = beg + tid; i < end; i += 256)
        m = fmaxf(m, gp[i] + gp[N_NODES + i]);
#pragma unroll
    for (int o = 32; o > 0; o >>= 1) m = fmaxf(m, __shfl_xor(m, o));
    if ((tid & 63) == 0) red[tid >> 6] = m;
    __syncthreads();
    m = fmaxf(fmaxf(red[0], red[1]), fmaxf(red[2], red[3]));
    __syncthreads();
    float s = 0.f;
    for (int i = beg + tid; i < end; i += 256)
        s += __expf(gp[i] + gp[N_NODES + i] - m);
#pragma unroll
    for (int o = 32; o > 0; o >>= 1) s += __shfl_xor(s, o);
    if ((tid & 63) == 0) red[tid >> 6] = s;
    __syncthreads();
    float inv = 1.f / (red[0] + red[1] + red[2] + red[3]);
    const int p = tid >> 7;
    const int c = tid & 127;
    float acc = 0.f;
    for (int i = beg + chunk * 2 + p; i < end; i += 16) {
        float w = __expf(gp[i] + gp[N_NODES + i] - m);
        acc += w * __bfloat162float(feat[(size_t)i * DIM + c]);
    }
    acc *= inv;
    atomicAdd(&out_acc[g * DIM + c], acc);
}

__global__ void writeout_kernel(const float* __restrict__ out_acc,
                                void* __restrict__ out, const int* __restrict__ flag) {
    int i = blockIdx.x * 256 + threadIdx.x;
    if (i < NGRAPH * DIM) {
        float v = out_acc[i] * (1.f / 3.f);
        if ((*flag) > 8) ((float*)out)[i] = v;
        else ((bf16*)out)[i] = __float2bfloat16(v);
    }
}

// ---------------- host launcher ----------------
extern "C" void kernel_launch(void* const* d_in, const int* in_sizes, int n_in,
                              void* d_out, int out_size, void* d_ws, size_t ws_size,
                              hipStream_t stream)
{
    const void* feat_in = d_in[0];
    const int* src = (const int*)d_in[1];
    const int* dst = (const int*)d_in[2];
    const int* gid = (const int*)d_in[3];

    char* base = (char*)d_ws;
    size_t off = 0;
    auto carve = [&](size_t bytes) -> void* {
        void* p = base + off;
        off = (off + bytes + 255) & ~(size_t)255;
        return p;
    };
    int* dflag = (int*)carve(256);   // NOT zeroed; init block 0 stores it
    size_t zbytes = sizeof(int) * 2 * N_NODES + sizeof(float) * NGRAPH * DIM;
    char* zreg  = (char*)carve(zbytes);
    int* deg    = (int*)zreg;
    int* cursor = deg + N_NODES;
    float* out_acc = (float*)(cursor + N_NODES);
    float* gpart3 = (float*)carve(sizeof(float) * LAYERS * 2 * N_NODES);
    int* rp     = (int*)carve(sizeof(int) * (N_NODES + 1));
    int* gptr   = (int*)carve(sizeof(int) * (NGRAPH + 1));
    int* esrc   = (int*)carve(sizeof(int) * N_EDGES);
    float* s_bufA = (float*)carve(sizeof(float) * N_NODES * 8);
    float* s_bufB = (float*)carve(sizeof(float) * N_NODES * 8);
    float* vcat = (float*)carve(sizeof(float) * LAYERS * 6 * 128);
    bf16* mcat  = (bf16*)carve(sizeof(bf16) * LAYERS * 128 * 384);
    bf16* featA = (bf16*)carve(sizeof(bf16) * N_NODES * DIM);
    bf16* featB = (bf16*)carve(sizeof(bf16) * N_NODES * DIM);
    bf16* cfc   = (bf16*)carve(sizeof(bf16) * LAYERS * HEADS * DIM * DIM);
    bf16* cans  = (bf16*)carve(sizeof(bf16) * LAYERS * HEADS * DIM);
    bf16* cand  = (bf16*)carve(sizeof(bf16) * LAYERS * HEADS * DIM);
    bf16* ctw   = (bf16*)carve(sizeof(bf16) * LAYERS * DIM * HEADS * DIM);
    bf16* ctb   = (bf16*)carve(sizeof(bf16) * LAYERS * DIM);
    bf16* cp1w  = (bf16*)carve(sizeof(bf16) * LAYERS * 2 * DIM * DIM);
    bf16* cp1b  = (bf16*)carve(sizeof(bf16) * LAYERS * 2 * DIM);
    bf16* cp2w  = (bf16*)carve(sizeof(bf16) * LAYERS * 2 * DIM);
    carve(131072);   // pad: GEMM A-tile tail overreads

    if (off > ws_size) {
        sentinel_kernel<<<(out_size + 255) / 256, 256, 0, stream>>>(
            (bf16*)d_out, out_size);
        return;
    }

    init_kernel<<<128, 256, 0, stream>>>(
        (unsigned*)zreg, (int)(zbytes / 4), (const unsigned short*)feat_in, dflag);

    CvtArgs ca;
    const int cvt_n[NCVT] = {
        N_NODES * DIM, LAYERS * HEADS * DIM * DIM, LAYERS * HEADS * DIM,
        LAYERS * HEADS * DIM, LAYERS * DIM * HEADS * DIM, LAYERS * DIM,
        LAYERS * 2 * DIM * DIM, LAYERS * 2 * DIM, LAYERS * 2 * DIM };
    bf16* cvt_dst[NCVT] = { featA, cfc, cans, cand, ctw, ctb, cp1w, cp1b, cp2w };
    const int cvt_src_idx[NCVT] = { 0, 4, 5, 6, 7, 8, 9, 10, 11 };
    int total4 = 0;
    for (int s = 0; s < NCVT; ++s) {
        ca.src[s] = d_in[cvt_src_idx[s]];
        ca.dst[s] = cvt_dst[s];
        ca.n[s] = cvt_n[s];
        ca.n4[s] = (cvt_n[s] + 3) / 4;
        total4 += ca.n4[s];
    }
    const int cvtBlocks = (total4 + 255) / 256;
    const int cntBlocks = (N_EDGES + 255) / 256;
    cvtcount_kernel<<<cvtBlocks + cntBlocks, 256, 0, stream>>>(
        ca, dflag, dst, deg, cvtBlocks);

    scan_gptr_kernel<<<1, 256, 0, stream>>>(deg, rp, gid, gptr);
    prep_kernel<<<LAYERS * 25, 256, 0, stream>>>(cfc, cans, cand, ctw, mcat, vcat);

    bf16* fin = featA;
    bf16* fout = featB;
    for (int d = 0; d < LAYERS; ++d) {
        float* gpart = gpart3 + (size_t)d * 2 * N_NODES;
        float* s_cur = (d & 1) ? s_bufB : s_bufA;
        float* s_next = (d & 1) ? s_bufA : s_bufB;
        const int poolBlocks = (d == 0) ? 0 : NGRAPH * 8;
        const int fillBlocks = (d == 0) ? cntBlocks : 0;
        const int scoreBlocks = (d == 0) ? NODE_BLOCKS : 0;
        poolfc_kernel<<<poolBlocks + fillBlocks + scoreBlocks, 256, 0, stream>>>(
            fin, (d == 0) ? nullptr : gpart3 + (size_t)(d - 1) * 2 * N_NODES,
            gptr, out_acc,
            vcat + (size_t)d * 6 * 128, s_cur,
            src, dst, rp, cursor, esrc, poolBlocks, fillBlocks);
        aggemm_kernel<<<NODE_BLOCKS, 256, 0, stream>>>(
            (const unsigned*)fin, rp, esrc, s_cur, s_next,
            mcat + (size_t)d * 128 * 384, ctb + (size_t)d * DIM, fout,
            (d < LAYERS - 1) ? vcat + (size_t)(d + 1) * 6 * 128 : nullptr,
            (d < LAYERS - 1) ? 1 : 0);
        gemm_mfma<2, 1><<<dim3(NODE_BLOCKS, 2), 256, 0, stream>>>(
            fout, cp1w + (size_t)d * 2 * DIM * DIM, nullptr,
            N_NODES, 2 * DIM, cp1b + (size_t)d * 2 * DIM, nullptr, 1,
            cp2w + (size_t)d * 2 * DIM, gpart);
        bf16* t = fin; fin = fout; fout = t;
    }
    pool_acc<<<dim3(NGRAPH, 8), 256, 0, stream>>>(
        fin, gpart3 + (size_t)2 * 2 * N_NODES, gptr, out_acc);
    writeout_kernel<<<(NGRAPH * DIM + 255) / 256, 256, 0, stream>>>(
        out_acc, d_out, dflag);
}

// Round 4
// 340.432 us; speedup vs baseline: 1.3378x; 1.3378x over previous
//
#include <hip/hip_runtime.h>
#include <hip/hip_bf16.h>

#define N_NODES 20000
#define N_EDGES 320000
#define DIM 128
#define HEADS 3
#define LAYERS 3
#define NGRAPH 64
#define NEG_SLOPE 0.2f
#define NODE_BLOCKS ((N_NODES + 63) / 64)   // 313

typedef const __hip_bfloat16* bfp;
typedef __hip_bfloat16 bf16;
typedef short v8s __attribute__((ext_vector_type(8)));
typedef float v4f __attribute__((ext_vector_type(4)));

#define GLD_LDS(gp, lp) \
    __builtin_amdgcn_global_load_lds( \
        (const __attribute__((address_space(1))) void*)(gp), \
        (__attribute__((address_space(3))) void*)(lp), 16, 0, 0)

__device__ __forceinline__ float b2f(unsigned short u) {
    return __uint_as_float(((unsigned)u) << 16);
}
__device__ __forceinline__ float lo2f(unsigned u) { return __uint_as_float(u << 16); }
__device__ __forceinline__ float hi2f(unsigned u) { return __uint_as_float(u & 0xffff0000u); }
__device__ __forceinline__ float leaky(float z) {
    return z >= 0.f ? z : NEG_SLOPE * z;
}
__device__ __forceinline__ unsigned packbf(float a, float b) {
    bf16 x = __float2bfloat16(a), y = __float2bfloat16(b);
    return (unsigned)*(unsigned short*)&x | ((unsigned)*(unsigned short*)&y << 16);
}
__device__ __forceinline__ unsigned short f2bfbits(float v) {
    bf16 x = __float2bfloat16(v);
    return *(unsigned short*)&x;
}

// XOR-swizzled 32-col chunk staging (validated R13)
__device__ __forceinline__ void stage_swz(const short* base, int t0, int K,
                                          int k0, short* lds, int gidx) {
    int row = gidx >> 2, pos = gidx & 3;
    int kch = pos ^ ((row >> 1) & 3);
    GLD_LDS(base + (size_t)(t0 + row) * K + k0 + kch * 8, lds + gidx * 8);
}
__device__ __forceinline__ v8s fragx(const short* lds, int R, int q) {
    int g = R * 4 + (q ^ ((R >> 1) & 3));
    return *(const v8s*)(lds + g * 8);
}

// Full-panel staging: A 64x128 = 1024 granules; B 128x128 = 2048 granules.
__device__ __forceinline__ void stage_panelA(const short* base, int t0, int K,
                                             int k0, short* lds, int tid) {
#pragma unroll
    for (int j = 0; j < 4; ++j) {
        int g = j * 256 + tid;
        stage_swz(base, t0, K, k0 + (g >> 8) * 32, lds + (g >> 8) * 2048, g & 255);
    }
}
__device__ __forceinline__ void stage_panelB(const short* base, int t0, int K,
                                             int k0, short* lds, int tid) {
#pragma unroll
    for (int j = 0; j < 8; ++j) {
        int g = j * 256 + tid;
        stage_swz(base, t0, K, k0 + (g >> 9) * 32, lds + (g >> 9) * 4096, g & 511);
    }
}

// ---------------- init: zero workspace region + dtype detect ----------------
__global__ void init_kernel(unsigned* __restrict__ z, int nzd,
                            const unsigned short* __restrict__ probe,
                            int* __restrict__ dflag) {
    int gid = blockIdx.x * 256 + threadIdx.x;
    for (int i = gid; i < nzd; i += gridDim.x * 256) z[i] = 0u;
    if (blockIdx.x == 0) {
        int c = 0;
#pragma unroll
        for (int j = 0; j < 64; ++j) {
            unsigned short u = probe[threadIdx.x * 64 + j];
            c += (((u >> 7) & 0xFF) >= 140) ? 1 : 0;
        }
        for (int o = 32; o > 0; o >>= 1) c += __shfl_down(c, o);
        __shared__ int r[4];
        if ((threadIdx.x & 63) == 0) r[threadIdx.x >> 6] = c;
        __syncthreads();
        if (threadIdx.x == 0) *dflag = r[0] + r[1] + r[2] + r[3];
    }
}

// ---------------- fused cvt (all float inputs -> bf16) + edge histogram -----
#define NCVT 9
struct CvtArgs {
    const void* src[NCVT];
    bf16* dst[NCVT];
    int n4[NCVT];
    int n[NCVT];
};
__global__ void cvtcount_kernel(CvtArgs args, const int* __restrict__ flag,
                                const int* __restrict__ dst, int* __restrict__ deg,
                                int cvtBlocks) {
    if ((int)blockIdx.x >= cvtBlocks) {
        int e = (blockIdx.x - cvtBlocks) * 256 + threadIdx.x;
        if (e < N_EDGES) atomicAdd(&deg[dst[e]], 1);
        return;
    }
    int i = blockIdx.x * 256 + threadIdx.x;
    int f = (*flag) > 8;
#pragma unroll
    for (int s = 0; s < NCVT; ++s) {
        int ns4 = args.n4[s];
        if (i < ns4) {
            int ns = args.n[s];
            int base = i * 4;
            bf16* dstp = args.dst[s];
            if (f) {
                const float* sp = (const float*)args.src[s];
                if (base + 3 < ns) {
                    float4 v = *(const float4*)(sp + base);
                    ushort4 pk = { f2bfbits(v.x), f2bfbits(v.y),
                                   f2bfbits(v.z), f2bfbits(v.w) };
                    *(ushort4*)(dstp + base) = pk;
                } else {
                    for (int j = 0; j < 4 && base + j < ns; ++j)
                        dstp[base + j] = __float2bfloat16(sp[base + j]);
                }
            } else {
                const bf16* sp = (const bf16*)args.src[s];
                if (base + 3 < ns) {
                    *(ushort4*)(dstp + base) = *(const ushort4*)(sp + base);
                } else {
                    for (int j = 0; j < 4 && base + j < ns; ++j)
                        dstp[base + j] = sp[base + j];
                }
            }
            return;
        }
        i -= ns4;
    }
}

// ---------------- fused: deg scan (shfl block-scan) + gptr binary search ----
__global__ void scan_gptr_kernel(const int* __restrict__ cnt, int* __restrict__ ptr,
                                 const int* __restrict__ gid, int* __restrict__ gptr) {
    int tid = threadIdx.x;
    if (tid <= NGRAPH) {
        int lo = 0, hi = N_NODES;
        while (lo < hi) {
            int mid = (lo + hi) >> 1;
            if (gid[mid] < tid) lo = mid + 1; else hi = mid;
        }
        gptr[tid] = lo;
    }
    const int chunk = (N_NODES + 255) / 256;
    int b = tid * chunk, e = min(b + chunk, N_NODES);
    int loc = 0;
    for (int i = b; i < e; ++i) loc += cnt[i];
    int lane = tid & 63, wv = tid >> 6;
    int v = loc;
#pragma unroll
    for (int o = 1; o < 64; o <<= 1) {
        int t = __shfl_up(v, o);
        if (lane >= o) v += t;
    }
    __shared__ int wsum[4];
    if (lane == 63) wsum[wv] = v;
    __syncthreads();
    int wo = 0;
    for (int j = 0; j < wv; ++j) wo += wsum[j];
    int run = wo + v - loc;
    if (tid == 255) ptr[N_NODES] = wsum[0] + wsum[1] + wsum[2] + wsum[3];
    for (int i = b; i < e; ++i) { ptr[i] = run; run += cnt[i]; }
}

__global__ void sentinel_kernel(bf16* out, int n) {
    int i = blockIdx.x * 256 + threadIdx.x;
    if (i < n) out[i] = __float2bfloat16(2.0f);
}

// ---------------- prep: vcat = fcW^T @ a  and  Mcat = tw_h @ fcW_h ----------
__global__ __launch_bounds__(256) void prep_kernel(
    const bf16* __restrict__ cfc, const bf16* __restrict__ cans,
    const bf16* __restrict__ cand, const bf16* __restrict__ ctw,
    bf16* __restrict__ mcat, float* __restrict__ vcat)
{
    const int l = blockIdx.x / 25;
    const int b = blockIdx.x % 25;
    const bf16* fc = cfc + (size_t)l * 384 * 128;
    if (b < 24) {
        const int h = b >> 3, kc = b & 7;
        const bf16* tw = ctw + (size_t)l * 128 * 384;
        bf16* mc = mcat + (size_t)l * 128 * 384;
        const int d = threadIdx.x & 127;
        const int kh = threadIdx.x >> 7;
        const int k0 = kc * 16 + kh * 8;
        float acc[8] = {0.f, 0.f, 0.f, 0.f, 0.f, 0.f, 0.f, 0.f};
        for (int j = 0; j < 128; ++j) {
            float w = __bfloat162float(tw[(size_t)d * 384 + h * 128 + j]);
            v8s fv = *(const v8s*)(fc + (size_t)(h * 128 + j) * 128 + k0);
#pragma unroll
            for (int i = 0; i < 8; ++i)
                acc[i] += w * b2f((unsigned short)fv[i]);
        }
        v8s ov;
#pragma unroll
        for (int i = 0; i < 8; ++i) ov[i] = (short)f2bfbits(acc[i]);
        *(v8s*)(mc + (size_t)d * 384 + h * 128 + k0) = ov;
    } else {
        const int k = threadIdx.x & 127;
        const int grp = threadIdx.x >> 7;   // 0 = ns, 1 = nd
        const bf16* av = (grp ? cand : cans) + (size_t)l * 384;
        float a0 = 0.f, a1 = 0.f, a2 = 0.f;
        for (int j = 0; j < 128; ++j) {
            a0 += __bfloat162float(av[j])       * __bfloat162float(fc[(size_t)j * 128 + k]);
            a1 += __bfloat162float(av[128 + j]) * __bfloat162float(fc[(size_t)(128 + j) * 128 + k]);
            a2 += __bfloat162float(av[256 + j]) * __bfloat162float(fc[(size_t)(256 + j) * 128 + k]);
        }
        float* vc = vcat + (size_t)l * 6 * 128;
        vc[(grp * 3 + 0) * 128 + k] = a0;
        vc[(grp * 3 + 1) * 128 + k] = a1;
        vc[(grp * 3 + 2) * 128 + k] = a2;
    }
}

// ---------------- score block: s_all[n][{0..2,4..6}] = feat[n]·vcat[c] ------
__device__ __forceinline__ void score_block(
    const unsigned* __restrict__ featdw, const float* __restrict__ vc,
    float* __restrict__ s_all, int blk, int tid)
{
    const int wv = tid >> 6, lane = tid & 63;
    float2 vv0 = *(const float2*)(vc + 0 * 128 + lane * 2);
    float2 vv1 = *(const float2*)(vc + 1 * 128 + lane * 2);
    float2 vv2 = *(const float2*)(vc + 2 * 128 + lane * 2);
    float2 vv3 = *(const float2*)(vc + 3 * 128 + lane * 2);
    float2 vv4 = *(const float2*)(vc + 4 * 128 + lane * 2);
    float2 vv5 = *(const float2*)(vc + 5 * 128 + lane * 2);
    const int nbase = blk * 64 + wv * 16;
#pragma unroll 1
    for (int t = 0; t < 16; ++t) {
        const int n = nbase + t;
        if (n >= N_NODES) return;
        unsigned u = featdw[(size_t)n * 64 + lane];
        float lo = lo2f(u), hi = hi2f(u);
        float p0 = lo * vv0.x + hi * vv0.y;
        float p1 = lo * vv1.x + hi * vv1.y;
        float p2 = lo * vv2.x + hi * vv2.y;
        float p3 = lo * vv3.x + hi * vv3.y;
        float p4 = lo * vv4.x + hi * vv4.y;
        float p5 = lo * vv5.x + hi * vv5.y;
#pragma unroll
        for (int o = 1; o < 64; o <<= 1) {
            p0 += __shfl_xor(p0, o); p1 += __shfl_xor(p1, o);
            p2 += __shfl_xor(p2, o); p3 += __shfl_xor(p3, o);
            p4 += __shfl_xor(p4, o); p5 += __shfl_xor(p5, o);
        }
        float outv = p0;
        outv = (lane == 1) ? p1 : outv;
        outv = (lane == 2) ? p2 : outv;
        outv = (lane == 4) ? p3 : outv;
        outv = (lane == 5) ? p4 : outv;
        outv = (lane == 6) ? p5 : outv;
        if (lane < 7 && lane != 3)
            s_all[(size_t)n * 8 + lane] = outv;
    }
}

// ---------------- merged: pool(d-1) | fill(d==0) | score(d==0) --------------
__global__ __launch_bounds__(256) void poolfc_kernel(
    const bf16* __restrict__ pfeat, const float* __restrict__ gp,
    const int* __restrict__ gptr, float* __restrict__ out_acc,
    const float* __restrict__ vc, float* __restrict__ s_all,
    const int* __restrict__ src, const int* __restrict__ dst,
    const int* __restrict__ rp, int* __restrict__ cursor,
    int* __restrict__ esrc,
    int poolBlocks, int fillBlocks)
{
    __shared__ float red[4];
    const int tid = threadIdx.x;
    if ((int)blockIdx.x < poolBlocks) {
        const int g = blockIdx.x >> 3;
        const int chunk = blockIdx.x & 7;
        const int beg = gptr[g], end = gptr[g + 1];
        if (beg >= end) return;
        float m = -1e30f;
        for (int i = beg + tid; i < end; i += 256)
            m = fmaxf(m, gp[i]);
#pragma unroll
        for (int o = 32; o > 0; o >>= 1) m = fmaxf(m, __shfl_xor(m, o));
        if ((tid & 63) == 0) red[tid >> 6] = m;
        __syncthreads();
        m = fmaxf(fmaxf(red[0], red[1]), fmaxf(red[2], red[3]));
        __syncthreads();
        float s = 0.f;
        for (int i = beg + tid; i < end; i += 256)
            s += __expf(gp[i] - m);
#pragma unroll
        for (int o = 32; o > 0; o >>= 1) s += __shfl_xor(s, o);
        if ((tid & 63) == 0) red[tid >> 6] = s;
        __syncthreads();
        float inv = 1.f / (red[0] + red[1] + red[2] + red[3]);
        const int p = tid >> 7;
        const int c = tid & 127;
        float acc = 0.f;
        for (int i = beg + chunk * 2 + p; i < end; i += 16) {
            float w = __expf(gp[i] - m);
            acc += w * __bfloat162float(pfeat[(size_t)i * DIM + c]);
        }
        acc *= inv;
        atomicAdd(&out_acc[g * DIM + c], acc);
        return;
    }
    if ((int)blockIdx.x < poolBlocks + fillBlocks) {
        int e = (blockIdx.x - poolBlocks) * 256 + tid;
        if (e < N_EDGES) {
            int d = dst[e];
            int pos = rp[d] + atomicAdd(&cursor[d], 1);
            esrc[pos] = src[e];
        }
        return;
    }
    const int blk = blockIdx.x - poolBlocks - fillBlocks;
    score_block((const unsigned*)pfeat, vc, s_all, blk, tid);
}

// ---------------- aggregate (R2-proven): wave/node, 256 B feat gather -------
__global__ __launch_bounds__(256) void agg_kernel(
    const unsigned* __restrict__ featdw, const int* __restrict__ rp,
    const int* __restrict__ esrc, const float* __restrict__ s_all,
    bf16* __restrict__ aggF)
{
    __shared__ float4 pv[4][64];
    const int wv = threadIdx.x >> 6;
    const int lane = threadIdx.x & 63;
    const int node = blockIdx.x * 4 + wv;
    if (node >= N_NODES) return;
    const int beg = rp[node], end = rp[node + 1];
    const int cnt = end - beg;
    unsigned* outp = (unsigned*)(aggF + (size_t)node * (HEADS * DIM));
    if (cnt <= 0) {
        outp[lane] = 0u; outp[64 + lane] = 0u; outp[128 + lane] = 0u;
        return;
    }
    const float nd0 = s_all[(size_t)node * 8 + 4];
    const float nd1 = s_all[(size_t)node * 8 + 5];
    const float nd2 = s_all[(size_t)node * 8 + 6];
    float sl0 = 0.f, sl1 = 0.f, sl2 = 0.f;
    float a00 = 0.f, a01 = 0.f, a10 = 0.f, a11 = 0.f, a20 = 0.f, a21 = 0.f;
    for (int c0 = 0; c0 < cnt; c0 += 64) {
        const int ce = min(64, cnt - c0);
        if (lane < ce) {
            int s = esrc[beg + c0 + lane];
            float4 q = *(const float4*)(s_all + (size_t)s * 8);
            float4 r;
            r.x = __expf(leaky(q.x + nd0));
            r.y = __expf(leaky(q.y + nd1));
            r.z = __expf(leaky(q.z + nd2));
            r.w = __int_as_float(s);
            sl0 += r.x; sl1 += r.y; sl2 += r.z;
            pv[wv][lane] = r;
        }
#pragma unroll 8
        for (int j = 0; j < ce; ++j) {
            float4 e = pv[wv][j];              // broadcast ds_read_b128
            int s = __float_as_int(e.w);
            unsigned u = featdw[(size_t)s * 64 + lane];   // 256 B/wave, coalesced
            float lo = lo2f(u), hi = hi2f(u);
            a00 += e.x * lo; a01 += e.x * hi;
            a10 += e.y * lo; a11 += e.y * hi;
            a20 += e.z * lo; a21 += e.z * hi;
        }
    }
#pragma unroll
    for (int o = 1; o < 64; o <<= 1) {
        sl0 += __shfl_xor(sl0, o);
        sl1 += __shfl_xor(sl1, o);
        sl2 += __shfl_xor(sl2, o);
    }
    const float i0 = 1.f / sl0, i1 = 1.f / sl1, i2 = 1.f / sl2;
    outp[lane]       = packbf(a00 * i0, a01 * i0);
    outp[64 + lane]  = packbf(a10 * i1, a11 * i1);
    outp[128 + lane] = packbf(a20 * i2, a21 * i2);
}

// ---------------- fused dense chain: trans-GEMM + scores(d+1) + gate --------
// Block = 64 rows. Main GEMM aggF(64x384) @ Mcat^T -> v (+bias,relu,resid).
// Epilogue writes C, folds next-layer score dots (f32), stores v-tile into
// lsA in fragx layout (wave-local rows: no cross-wave dependency). Then the
// gate MLP GEMM runs from lsA vs p1w (2 halves of 128 cols staged in lsB),
// relu·p2w row-reduce -> single gpart[m]. 48 KB LDS, 3 blocks/CU.
__global__ __launch_bounds__(256) void fusedgemm_kernel(
    const bf16* __restrict__ A, const bf16* __restrict__ B,
    bf16* __restrict__ C, const bf16* __restrict__ bias,
    const bf16* __restrict__ resid, int do_relu,
    const bf16* __restrict__ p1w, const bf16* __restrict__ p1b,
    const bf16* __restrict__ p2w, float* __restrict__ gpart,
    const float* __restrict__ vc_next, float* __restrict__ s_next)
{
    __shared__ short lsA[8192];
    __shared__ short lsB[16384];
    const int tid = threadIdx.x;
    const int wv = tid >> 6, lane = tid & 63;
    const int quad = lane >> 4, r16 = lane & 15;
    const int m0 = blockIdx.x * 64;
    const short* As = (const short*)A;
    const short* Bs = (const short*)B;

    v4f acc[8];
#pragma unroll
    for (int t = 0; t < 8; ++t) acc[t] = (v4f){0.f, 0.f, 0.f, 0.f};

#pragma unroll
    for (int ks = 0; ks < 3; ++ks) {
        const int k0 = ks * 128;
        stage_panelA(As, m0, 384, k0, lsA, tid);
        stage_panelB(Bs, 0, 384, k0, lsB, tid);
        __syncthreads();
#pragma unroll
        for (int c = 0; c < 4; ++c) {
            v8s a = fragx(lsA + c * 2048, wv * 16 + r16, quad);
#pragma unroll
            for (int t = 0; t < 8; ++t) {
                v8s b = fragx(lsB + c * 4096, t * 16 + r16, quad);
                acc[t] = __builtin_amdgcn_mfma_f32_16x16x32_bf16(a, b, acc[t], 0, 0, 0);
            }
        }
        if (ks + 1 < 3) __syncthreads();
    }

    // ---- epilogue: v, C write, next-layer scores, v -> lsA (fragx) ----
    const int mb = wv * 16;
    float bbv[8];
#pragma unroll
    for (int t = 0; t < 8; ++t) bbv[t] = __bfloat162float(bias[t * 16 + r16]);
    float sc0[4], sc1[4], sc2[4], sc3[4], sc4[4], sc5[4];
#pragma unroll
    for (int reg = 0; reg < 4; ++reg) {
        sc0[reg] = 0.f; sc1[reg] = 0.f; sc2[reg] = 0.f;
        sc3[reg] = 0.f; sc4[reg] = 0.f; sc5[reg] = 0.f;
    }
    __syncthreads();   // all waves done with main-GEMM LDS reads
#pragma unroll
    for (int t = 0; t < 8; ++t) {
        const int n = t * 16 + r16;
        float v0 = vc_next ? vc_next[0 * 128 + n] : 0.f;
        float v1 = vc_next ? vc_next[1 * 128 + n] : 0.f;
        float v2 = vc_next ? vc_next[2 * 128 + n] : 0.f;
        float v3 = vc_next ? vc_next[3 * 128 + n] : 0.f;
        float v4 = vc_next ? vc_next[4 * 128 + n] : 0.f;
        float v5 = vc_next ? vc_next[5 * 128 + n] : 0.f;
        const int cch = n >> 5, nc = n & 31, qq = nc >> 3, e = nc & 7;
#pragma unroll
        for (int reg = 0; reg < 4; ++reg) {
            const int R = mb + quad * 4 + reg;
            const int m = m0 + R;
            float v = acc[t][reg] + bbv[t];
            if (do_relu) v = fmaxf(v, 0.f);
            if (m < N_NODES) {
                v += __bfloat162float(resid[(size_t)m * 128 + n]);
                C[(size_t)m * 128 + n] = __float2bfloat16(v);
            } else {
                v = 0.f;
            }
            const int pos = qq ^ ((R >> 1) & 3);
            lsA[cch * 2048 + (R * 4 + pos) * 8 + e] = (short)f2bfbits(v);
            sc0[reg] += v * v0; sc1[reg] += v * v1; sc2[reg] += v * v2;
            sc3[reg] += v * v3; sc4[reg] += v * v4; sc5[reg] += v * v5;
        }
    }
    if (vc_next) {
#pragma unroll
        for (int reg = 0; reg < 4; ++reg) {
#pragma unroll
            for (int o = 1; o < 16; o <<= 1) {
                sc0[reg] += __shfl_xor(sc0[reg], o);
                sc1[reg] += __shfl_xor(sc1[reg], o);
                sc2[reg] += __shfl_xor(sc2[reg], o);
                sc3[reg] += __shfl_xor(sc3[reg], o);
                sc4[reg] += __shfl_xor(sc4[reg], o);
                sc5[reg] += __shfl_xor(sc5[reg], o);
            }
            const int m = m0 + mb + quad * 4 + reg;
            if (r16 == 0 && m < N_NODES) {
                s_next[(size_t)m * 8 + 0] = sc0[reg];
                s_next[(size_t)m * 8 + 1] = sc1[reg];
                s_next[(size_t)m * 8 + 2] = sc2[reg];
                s_next[(size_t)m * 8 + 4] = sc3[reg];
                s_next[(size_t)m * 8 + 5] = sc4[reg];
                s_next[(size_t)m * 8 + 6] = sc5[reg];
            }
        }
    }

    // ---- gate MLP GEMM from lsA vs p1w halves ----
    float gacc[4] = {0.f, 0.f, 0.f, 0.f};
#pragma unroll 1
    for (int hh = 0; hh < 2; ++hh) {
        __syncthreads();   // lsB free (and drains lsA v-tile writes at hh=0)
        stage_panelB((const short*)p1w, hh * 128, 128, 0, lsB, tid);
        __syncthreads();
        v4f a2[8];
#pragma unroll
        for (int t = 0; t < 8; ++t) a2[t] = (v4f){0.f, 0.f, 0.f, 0.f};
#pragma unroll
        for (int c = 0; c < 4; ++c) {
            v8s a = fragx(lsA + c * 2048, wv * 16 + r16, quad);
#pragma unroll
            for (int t = 0; t < 8; ++t) {
                v8s b = fragx(lsB + c * 4096, t * 16 + r16, quad);
                a2[t] = __builtin_amdgcn_mfma_f32_16x16x32_bf16(a, b, a2[t], 0, 0, 0);
            }
        }
#pragma unroll
        for (int t = 0; t < 8; ++t) {
            const int n = hh * 128 + t * 16 + r16;
            float b1 = __bfloat162float(p1b[n]);
            float pw = __bfloat162float(p2w[n]);
#pragma unroll
            for (int reg = 0; reg < 4; ++reg)
                gacc[reg] += fmaxf(a2[t][reg] + b1, 0.f) * pw;
        }
    }
#pragma unroll
    for (int reg = 0; reg < 4; ++reg) {
        float g = gacc[reg];
#pragma unroll
        for (int o = 1; o < 16; o <<= 1) g += __shfl_xor(g, o);
        const int m = m0 + mb + quad * 4 + reg;
        if (r16 == 0 && m < N_NODES) gpart[m] = g;
    }
}

// ---------------- standalone final pool (no fence — R20 errata) -------------
__global__ void __launch_bounds__(256) pool_acc(
    const bf16* __restrict__ feat, const float* __restrict__ gp,
    const int* __restrict__ gptr, float* __restrict__ out_acc)
{
    const int g = blockIdx.x;
    const int chunk = blockIdx.y;
    const int tid = threadIdx.x;
    const int beg = gptr[g], end = gptr[g + 1];
    if (beg >= end) return;
    __shared__ float red[4];
    float m = -1e30f;
    for (int i = beg + tid; i < end; i += 256)
        m = fmaxf(m, gp[i]);
#pragma unroll
    for (int o = 32; o > 0; o >>= 1) m = fmaxf(m, __shfl_xor(m, o));
    if ((tid & 63) == 0) red[tid >> 6] = m;
    __syncthreads();
    m = fmaxf(fmaxf(red[0], red[1]), fmaxf(red[2], red[3]));
    __syncthreads();
    float s = 0.f;
    for (int i = beg + tid; i < end; i += 256)
        s += __expf(gp[i] - m);
#pragma unroll
    for (int o = 32; o > 0; o >>= 1) s += __shfl_xor(s, o);
    if ((tid & 63) == 0) red[tid >> 6] = s;
    __syncthreads();
    float inv = 1.f / (red[0] + red[1] + red[2] + red[3]);
    const int p = tid >> 7;
    const int c = tid & 127;
    float acc = 0.f;
    for (int i = beg + chunk * 2 + p; i < end; i += 16) {
        float w = __expf(gp[i] - m);
        acc += w * __bfloat162float(feat[(size_t)i * DIM + c]);
    }
    acc *= inv;
    atomicAdd(&out_acc[g * DIM + c], acc);
}

__global__ void writeout_kernel(const float* __restrict__ out_acc,
                                void* __restrict__ out, const int* __restrict__ flag) {
    int i = blockIdx.x * 256 + threadIdx.x;
    if (i < NGRAPH * DIM) {
        float v = out_acc[i] * (1.f / 3.f);
        if ((*flag) > 8) ((float*)out)[i] = v;
        else ((bf16*)out)[i] = __float2bfloat16(v);
    }
}

// ---------------- host launcher ----------------
extern "C" void kernel_launch(void* const* d_in, const int* in_sizes, int n_in,
                              void* d_out, int out_size, void* d_ws, size_t ws_size,
                              hipStream_t stream)
{
    const void* feat_in = d_in[0];
    const int* src = (const int*)d_in[1];
    const int* dst = (const int*)d_in[2];
    const int* gid = (const int*)d_in[3];

    char* base = (char*)d_ws;
    size_t off = 0;
    auto carve = [&](size_t bytes) -> void* {
        void* p = base + off;
        off = (off + bytes + 255) & ~(size_t)255;
        return p;
    };
    int* dflag = (int*)carve(256);   // NOT zeroed; init block 0 stores it
    size_t zbytes = sizeof(int) * 2 * N_NODES + sizeof(float) * NGRAPH * DIM;
    char* zreg  = (char*)carve(zbytes);
    int* deg    = (int*)zreg;
    int* cursor = deg + N_NODES;
    float* out_acc = (float*)(cursor + N_NODES);
    float* gpart3 = (float*)carve(sizeof(float) * LAYERS * N_NODES);
    int* rp     = (int*)carve(sizeof(int) * (N_NODES + 1));
    int* gptr   = (int*)carve(sizeof(int) * (NGRAPH + 1));
    int* esrc   = (int*)carve(sizeof(int) * N_EDGES);
    float* s_bufA = (float*)carve(sizeof(float) * N_NODES * 8);
    float* s_bufB = (float*)carve(sizeof(float) * N_NODES * 8);
    float* vcat = (float*)carve(sizeof(float) * LAYERS * 6 * 128);
    bf16* mcat  = (bf16*)carve(sizeof(bf16) * LAYERS * 128 * 384);
    bf16* featA = (bf16*)carve(sizeof(bf16) * N_NODES * DIM);
    bf16* featB = (bf16*)carve(sizeof(bf16) * N_NODES * DIM);
    bf16* cfc   = (bf16*)carve(sizeof(bf16) * LAYERS * HEADS * DIM * DIM);
    bf16* cans  = (bf16*)carve(sizeof(bf16) * LAYERS * HEADS * DIM);
    bf16* cand  = (bf16*)carve(sizeof(bf16) * LAYERS * HEADS * DIM);
    bf16* ctw   = (bf16*)carve(sizeof(bf16) * LAYERS * DIM * HEADS * DIM);
    bf16* ctb   = (bf16*)carve(sizeof(bf16) * LAYERS * DIM);
    bf16* cp1w  = (bf16*)carve(sizeof(bf16) * LAYERS * 2 * DIM * DIM);
    bf16* cp1b  = (bf16*)carve(sizeof(bf16) * LAYERS * 2 * DIM);
    bf16* cp2w  = (bf16*)carve(sizeof(bf16) * LAYERS * 2 * DIM);
    bf16* aggF  = (bf16*)carve(sizeof(bf16) * N_NODES * HEADS * DIM);
    carve(131072);   // pad: GEMM A-tile tail overreads

    if (off > ws_size) {
        sentinel_kernel<<<(out_size + 255) / 256, 256, 0, stream>>>(
            (bf16*)d_out, out_size);
        return;
    }

    init_kernel<<<128, 256, 0, stream>>>(
        (unsigned*)zreg, (int)(zbytes / 4), (const unsigned short*)feat_in, dflag);

    CvtArgs ca;
    const int cvt_n[NCVT] = {
        N_NODES * DIM, LAYERS * HEADS * DIM * DIM, LAYERS * HEADS * DIM,
        LAYERS * HEADS * DIM, LAYERS * DIM * HEADS * DIM, LAYERS * DIM,
        LAYERS * 2 * DIM * DIM, LAYERS * 2 * DIM, LAYERS * 2 * DIM };
    bf16* cvt_dst[NCVT] = { featA, cfc, cans, cand, ctw, ctb, cp1w, cp1b, cp2w };
    const int cvt_src_idx[NCVT] = { 0, 4, 5, 6, 7, 8, 9, 10, 11 };
    int total4 = 0;
    for (int s = 0; s < NCVT; ++s) {
        ca.src[s] = d_in[cvt_src_idx[s]];
        ca.dst[s] = cvt_dst[s];
        ca.n[s] = cvt_n[s];
        ca.n4[s] = (cvt_n[s] + 3) / 4;
        total4 += ca.n4[s];
    }
    const int cvtBlocks = (total4 + 255) / 256;
    const int cntBlocks = (N_EDGES + 255) / 256;
    cvtcount_kernel<<<cvtBlocks + cntBlocks, 256, 0, stream>>>(
        ca, dflag, dst, deg, cvtBlocks);

    scan_gptr_kernel<<<1, 256, 0, stream>>>(deg, rp, gid, gptr);
    prep_kernel<<<LAYERS * 25, 256, 0, stream>>>(cfc, cans, cand, ctw, mcat, vcat);

    bf16* fin = featA;
    bf16* fout = featB;
    for (int d = 0; d < LAYERS; ++d) {
        float* s_cur = (d & 1) ? s_bufB : s_bufA;
        float* s_next = (d & 1) ? s_bufA : s_bufB;
        const int poolBlocks = (d == 0) ? 0 : NGRAPH * 8;
        const int fillBlocks = (d == 0) ? cntBlocks : 0;
        const int scoreBlocks = (d == 0) ? NODE_BLOCKS : 0;
        poolfc_kernel<<<poolBlocks + fillBlocks + scoreBlocks, 256, 0, stream>>>(
            fin, (d == 0) ? nullptr : gpart3 + (size_t)(d - 1) * N_NODES,
            gptr, out_acc,
            vcat + (size_t)d * 6 * 128, s_cur,
            src, dst, rp, cursor, esrc, poolBlocks, fillBlocks);
        agg_kernel<<<(N_NODES + 3) / 4, 256, 0, stream>>>(
            (const unsigned*)fin, rp, esrc, s_cur, aggF);
        fusedgemm_kernel<<<NODE_BLOCKS, 256, 0, stream>>>(
            aggF, mcat + (size_t)d * 128 * 384, fout,
            ctb + (size_t)d * DIM, fin, (d < LAYERS - 1) ? 1 : 0,
            cp1w + (size_t)d * 2 * DIM * DIM, cp1b + (size_t)d * 2 * DIM,
            cp2w + (size_t)d * 2 * DIM, gpart3 + (size_t)d * N_NODES,
            (d < LAYERS - 1) ? vcat + (size_t)(d + 1) * 6 * 128 : nullptr,
            s_next);
        bf16* t = fin; fin = fout; fout = t;
    }
    pool_acc<<<dim3(NGRAPH, 8), 256, 0, stream>>>(
        fin, gpart3 + (size_t)2 * N_NODES, gptr, out_acc);
    writeout_kernel<<<(NGRAPH * DIM + 255) / 256, 256, 0, stream>>>(
        out_acc, d_out, dflag);
}

// Round 5
// 295.242 us; speedup vs baseline: 1.5426x; 1.1531x over previous
//
#include <hip/hip_runtime.h>
#include <hip/hip_bf16.h>

#define N_NODES 20000
#define N_EDGES 320000
#define DIM 128
#define HEADS 3
#define LAYERS 3
#define NGRAPH 64
#define NEG_SLOPE 0.2f
#define NODE_BLOCKS ((N_NODES + 63) / 64)   // 313
#define NBLK32 ((N_NODES + 31) / 32)        // 625 (exact: 625*32 = 20000)

typedef const __hip_bfloat16* bfp;
typedef __hip_bfloat16 bf16;
typedef short v8s __attribute__((ext_vector_type(8)));
typedef float v4f __attribute__((ext_vector_type(4)));

#define GLD_LDS(gp, lp) \
    __builtin_amdgcn_global_load_lds( \
        (const __attribute__((address_space(1))) void*)(gp), \
        (__attribute__((address_space(3))) void*)(lp), 16, 0, 0)

__device__ __forceinline__ float b2f(unsigned short u) {
    return __uint_as_float(((unsigned)u) << 16);
}
__device__ __forceinline__ float lo2f(unsigned u) { return __uint_as_float(u << 16); }
__device__ __forceinline__ float hi2f(unsigned u) { return __uint_as_float(u & 0xffff0000u); }
__device__ __forceinline__ float leaky(float z) {
    return z >= 0.f ? z : NEG_SLOPE * z;
}
__device__ __forceinline__ unsigned packbf(float a, float b) {
    bf16 x = __float2bfloat16(a), y = __float2bfloat16(b);
    return (unsigned)*(unsigned short*)&x | ((unsigned)*(unsigned short*)&y << 16);
}
__device__ __forceinline__ unsigned short f2bfbits(float v) {
    bf16 x = __float2bfloat16(v);
    return *(unsigned short*)&x;
}

// XOR-swizzled 32-col chunk staging (validated R13)
__device__ __forceinline__ void stage_swz(const short* base, int t0, int K,
                                          int k0, short* lds, int gidx) {
    int row = gidx >> 2, pos = gidx & 3;
    int kch = pos ^ ((row >> 1) & 3);
    GLD_LDS(base + (size_t)(t0 + row) * K + k0 + kch * 8, lds + gidx * 8);
}
__device__ __forceinline__ v8s fragx(const short* lds, int R, int q) {
    int g = R * 4 + (q ^ ((R >> 1) & 3));
    return *(const v8s*)(lds + g * 8);
}

// B panel: 128 rows x 128 k = 2048 granules, 4 chunks of 32k (stride 4096 sh)
__device__ __forceinline__ void stage_panelB(const short* base, int t0, int K,
                                             int k0, short* lds, int tid) {
#pragma unroll
    for (int j = 0; j < 8; ++j) {
        int g = j * 256 + tid;
        stage_swz(base, t0, K, k0 + (g >> 9) * 32, lds + (g >> 9) * 4096, g & 511);
    }
}
// A panel (BM=32): 32 rows x 128 k = 512 granules, 4 chunks (stride 1024 sh)
__device__ __forceinline__ void stage_panelA32(const short* base, int t0, int K,
                                               int k0, short* lds, int tid) {
#pragma unroll
    for (int j = 0; j < 2; ++j) {
        int g = j * 256 + tid;
        stage_swz(base, t0, K, k0 + (g >> 7) * 32, lds + (g >> 7) * 1024, g & 127);
    }
}

// ---------------- init: zero workspace region + dtype detect ----------------
__global__ void init_kernel(unsigned* __restrict__ z, int nzd,
                            const unsigned short* __restrict__ probe,
                            int* __restrict__ dflag) {
    int gid = blockIdx.x * 256 + threadIdx.x;
    for (int i = gid; i < nzd; i += gridDim.x * 256) z[i] = 0u;
    if (blockIdx.x == 0) {
        int c = 0;
#pragma unroll
        for (int j = 0; j < 64; ++j) {
            unsigned short u = probe[threadIdx.x * 64 + j];
            c += (((u >> 7) & 0xFF) >= 140) ? 1 : 0;
        }
        for (int o = 32; o > 0; o >>= 1) c += __shfl_down(c, o);
        __shared__ int r[4];
        if ((threadIdx.x & 63) == 0) r[threadIdx.x >> 6] = c;
        __syncthreads();
        if (threadIdx.x == 0) *dflag = r[0] + r[1] + r[2] + r[3];
    }
}

// ---------------- fused cvt (all float inputs -> bf16) + edge histogram -----
#define NCVT 9
struct CvtArgs {
    const void* src[NCVT];
    bf16* dst[NCVT];
    int n4[NCVT];
    int n[NCVT];
};
__global__ void cvtcount_kernel(CvtArgs args, const int* __restrict__ flag,
                                const int* __restrict__ dst, int* __restrict__ deg,
                                int cvtBlocks) {
    if ((int)blockIdx.x >= cvtBlocks) {
        int e = (blockIdx.x - cvtBlocks) * 256 + threadIdx.x;
        if (e < N_EDGES) atomicAdd(&deg[dst[e]], 1);
        return;
    }
    int i = blockIdx.x * 256 + threadIdx.x;
    int f = (*flag) > 8;
#pragma unroll
    for (int s = 0; s < NCVT; ++s) {
        int ns4 = args.n4[s];
        if (i < ns4) {
            int ns = args.n[s];
            int base = i * 4;
            bf16* dstp = args.dst[s];
            if (f) {
                const float* sp = (const float*)args.src[s];
                if (base + 3 < ns) {
                    float4 v = *(const float4*)(sp + base);
                    ushort4 pk = { f2bfbits(v.x), f2bfbits(v.y),
                                   f2bfbits(v.z), f2bfbits(v.w) };
                    *(ushort4*)(dstp + base) = pk;
                } else {
                    for (int j = 0; j < 4 && base + j < ns; ++j)
                        dstp[base + j] = __float2bfloat16(sp[base + j]);
                }
            } else {
                const bf16* sp = (const bf16*)args.src[s];
                if (base + 3 < ns) {
                    *(ushort4*)(dstp + base) = *(const ushort4*)(sp + base);
                } else {
                    for (int j = 0; j < 4 && base + j < ns; ++j)
                        dstp[base + j] = sp[base + j];
                }
            }
            return;
        }
        i -= ns4;
    }
}

__global__ void sentinel_kernel(bf16* out, int n) {
    int i = blockIdx.x * 256 + threadIdx.x;
    if (i < n) out[i] = __float2bfloat16(2.0f);
}

// ---------------- merged: prep (75 blocks) + deg-scan/gptr (1 block) --------
__global__ __launch_bounds__(256) void scanprep_kernel(
    const int* __restrict__ cnt, int* __restrict__ ptr,
    const int* __restrict__ gid, int* __restrict__ gptr,
    const bf16* __restrict__ cfc, const bf16* __restrict__ cans,
    const bf16* __restrict__ cand, const bf16* __restrict__ ctw,
    bf16* __restrict__ mcat, float* __restrict__ vcat)
{
    int tid = threadIdx.x;
    if ((int)blockIdx.x < LAYERS * 25) {
        const int l = blockIdx.x / 25;
        const int b = blockIdx.x % 25;
        const bf16* fc = cfc + (size_t)l * 384 * 128;
        if (b < 24) {
            const int h = b >> 3, kc = b & 7;
            const bf16* tw = ctw + (size_t)l * 128 * 384;
            bf16* mc = mcat + (size_t)l * 128 * 384;
            const int d = tid & 127;
            const int kh = tid >> 7;
            const int k0 = kc * 16 + kh * 8;
            float acc[8] = {0.f, 0.f, 0.f, 0.f, 0.f, 0.f, 0.f, 0.f};
            for (int j = 0; j < 128; ++j) {
                float w = __bfloat162float(tw[(size_t)d * 384 + h * 128 + j]);
                v8s fv = *(const v8s*)(fc + (size_t)(h * 128 + j) * 128 + k0);
#pragma unroll
                for (int i = 0; i < 8; ++i)
                    acc[i] += w * b2f((unsigned short)fv[i]);
            }
            v8s ov;
#pragma unroll
            for (int i = 0; i < 8; ++i) ov[i] = (short)f2bfbits(acc[i]);
            *(v8s*)(mc + (size_t)d * 384 + h * 128 + k0) = ov;
        } else {
            const int k = tid & 127;
            const int grp = tid >> 7;   // 0 = ns, 1 = nd
            const bf16* av = (grp ? cand : cans) + (size_t)l * 384;
            float a0 = 0.f, a1 = 0.f, a2 = 0.f;
            for (int j = 0; j < 128; ++j) {
                a0 += __bfloat162float(av[j])       * __bfloat162float(fc[(size_t)j * 128 + k]);
                a1 += __bfloat162float(av[128 + j]) * __bfloat162float(fc[(size_t)(128 + j) * 128 + k]);
                a2 += __bfloat162float(av[256 + j]) * __bfloat162float(fc[(size_t)(256 + j) * 128 + k]);
            }
            float* vc = vcat + (size_t)l * 6 * 128;
            vc[(grp * 3 + 0) * 128 + k] = a0;
            vc[(grp * 3 + 1) * 128 + k] = a1;
            vc[(grp * 3 + 2) * 128 + k] = a2;
        }
        return;
    }
    // ---- scan block ----
    if (tid <= NGRAPH) {
        int lo = 0, hi = N_NODES;
        while (lo < hi) {
            int mid = (lo + hi) >> 1;
            if (gid[mid] < tid) lo = mid + 1; else hi = mid;
        }
        gptr[tid] = lo;
    }
    const int chunk = (N_NODES + 255) / 256;
    int b = tid * chunk, e = min(b + chunk, N_NODES);
    int loc = 0;
    for (int i = b; i < e; ++i) loc += cnt[i];
    int lane = tid & 63, wv = tid >> 6;
    int v = loc;
#pragma unroll
    for (int o = 1; o < 64; o <<= 1) {
        int t = __shfl_up(v, o);
        if (lane >= o) v += t;
    }
    __shared__ int wsum[4];
    if (lane == 63) wsum[wv] = v;
    __syncthreads();
    int wo = 0;
    for (int j = 0; j < wv; ++j) wo += wsum[j];
    int run = wo + v - loc;
    if (tid == 255) ptr[N_NODES] = wsum[0] + wsum[1] + wsum[2] + wsum[3];
    for (int i = b; i < e; ++i) { ptr[i] = run; run += cnt[i]; }
}

// ---------------- score block: s_all[n][{0..2,4..6}] = feat[n]·vcat[c] ------
__device__ __forceinline__ void score_block(
    const unsigned* __restrict__ featdw, const float* __restrict__ vc,
    float* __restrict__ s_all, int blk, int tid)
{
    const int wv = tid >> 6, lane = tid & 63;
    float2 vv0 = *(const float2*)(vc + 0 * 128 + lane * 2);
    float2 vv1 = *(const float2*)(vc + 1 * 128 + lane * 2);
    float2 vv2 = *(const float2*)(vc + 2 * 128 + lane * 2);
    float2 vv3 = *(const float2*)(vc + 3 * 128 + lane * 2);
    float2 vv4 = *(const float2*)(vc + 4 * 128 + lane * 2);
    float2 vv5 = *(const float2*)(vc + 5 * 128 + lane * 2);
    const int nbase = blk * 64 + wv * 16;
#pragma unroll 1
    for (int t = 0; t < 16; ++t) {
        const int n = nbase + t;
        if (n >= N_NODES) return;
        unsigned u = featdw[(size_t)n * 64 + lane];
        float lo = lo2f(u), hi = hi2f(u);
        float p0 = lo * vv0.x + hi * vv0.y;
        float p1 = lo * vv1.x + hi * vv1.y;
        float p2 = lo * vv2.x + hi * vv2.y;
        float p3 = lo * vv3.x + hi * vv3.y;
        float p4 = lo * vv4.x + hi * vv4.y;
        float p5 = lo * vv5.x + hi * vv5.y;
#pragma unroll
        for (int o = 1; o < 64; o <<= 1) {
            p0 += __shfl_xor(p0, o); p1 += __shfl_xor(p1, o);
            p2 += __shfl_xor(p2, o); p3 += __shfl_xor(p3, o);
            p4 += __shfl_xor(p4, o); p5 += __shfl_xor(p5, o);
        }
        float outv = p0;
        outv = (lane == 1) ? p1 : outv;
        outv = (lane == 2) ? p2 : outv;
        outv = (lane == 4) ? p3 : outv;
        outv = (lane == 5) ? p4 : outv;
        outv = (lane == 6) ? p5 : outv;
        if (lane < 7 && lane != 3)
            s_all[(size_t)n * 8 + lane] = outv;
    }
}

// ---------------- layer-0 only: fill (CSR scatter) + score ------------------
__global__ __launch_bounds__(256) void fillscore_kernel(
    const bf16* __restrict__ pfeat,
    const float* __restrict__ vc, float* __restrict__ s_all,
    const int* __restrict__ src, const int* __restrict__ dst,
    const int* __restrict__ rp, int* __restrict__ cursor,
    int* __restrict__ esrc, int fillBlocks)
{
    const int tid = threadIdx.x;
    if ((int)blockIdx.x < fillBlocks) {
        int e = blockIdx.x * 256 + tid;
        if (e < N_EDGES) {
            int d = dst[e];
            int pos = rp[d] + atomicAdd(&cursor[d], 1);
            esrc[pos] = src[e];
        }
        return;
    }
    score_block((const unsigned*)pfeat, vc, s_all, blockIdx.x - fillBlocks, tid);
}

// ---------------- merged: pool(d-1) (512 blocks) + aggregate ----------------
// Pool and agg both only READ featdw (= layer input), so they co-launch.
// Pool blocks are BW-light and fill SIMD slots while agg waves sit in
// gather-latency. Agg: wave/node, 256 B coalesced feat-row gather.
__global__ __launch_bounds__(256) void aggpool_kernel(
    const unsigned* __restrict__ featdw, const int* __restrict__ rp,
    const int* __restrict__ esrc, const float* __restrict__ s_all,
    bf16* __restrict__ aggF, const float* __restrict__ gp,
    const int* __restrict__ gptr, float* __restrict__ out_acc,
    int poolBlocks)
{
    __shared__ float4 pv[4][64];
    __shared__ float red[4];
    const int tid = threadIdx.x;
    if ((int)blockIdx.x < poolBlocks) {
        const bf16* pfeat = (const bf16*)featdw;
        const int g = blockIdx.x >> 3;
        const int chunk = blockIdx.x & 7;
        const int beg = gptr[g], end = gptr[g + 1];
        if (beg >= end) return;
        float m = -1e30f;
        for (int i = beg + tid; i < end; i += 256)
            m = fmaxf(m, gp[i]);
#pragma unroll
        for (int o = 32; o > 0; o >>= 1) m = fmaxf(m, __shfl_xor(m, o));
        if ((tid & 63) == 0) red[tid >> 6] = m;
        __syncthreads();
        m = fmaxf(fmaxf(red[0], red[1]), fmaxf(red[2], red[3]));
        __syncthreads();
        float s = 0.f;
        for (int i = beg + tid; i < end; i += 256)
            s += __expf(gp[i] - m);
#pragma unroll
        for (int o = 32; o > 0; o >>= 1) s += __shfl_xor(s, o);
        if ((tid & 63) == 0) red[tid >> 6] = s;
        __syncthreads();
        float inv = 1.f / (red[0] + red[1] + red[2] + red[3]);
        const int p = tid >> 7;
        const int c = tid & 127;
        float acc = 0.f;
        for (int i = beg + chunk * 2 + p; i < end; i += 16) {
            float w = __expf(gp[i] - m);
            acc += w * __bfloat162float(pfeat[(size_t)i * DIM + c]);
        }
        acc *= inv;
        atomicAdd(&out_acc[g * DIM + c], acc);
        return;
    }
    const int wv = tid >> 6;
    const int lane = tid & 63;
    const int node = (blockIdx.x - poolBlocks) * 4 + wv;
    if (node >= N_NODES) return;
    const int beg = rp[node], end = rp[node + 1];
    const int cnt = end - beg;
    unsigned* outp = (unsigned*)(aggF + (size_t)node * (HEADS * DIM));
    if (cnt <= 0) {
        outp[lane] = 0u; outp[64 + lane] = 0u; outp[128 + lane] = 0u;
        return;
    }
    const float nd0 = s_all[(size_t)node * 8 + 4];
    const float nd1 = s_all[(size_t)node * 8 + 5];
    const float nd2 = s_all[(size_t)node * 8 + 6];
    float sl0 = 0.f, sl1 = 0.f, sl2 = 0.f;
    float a00 = 0.f, a01 = 0.f, a10 = 0.f, a11 = 0.f, a20 = 0.f, a21 = 0.f;
    for (int c0 = 0; c0 < cnt; c0 += 64) {
        const int ce = min(64, cnt - c0);
        if (lane < ce) {
            int s = esrc[beg + c0 + lane];
            float4 q = *(const float4*)(s_all + (size_t)s * 8);
            float4 r;
            r.x = __expf(leaky(q.x + nd0));
            r.y = __expf(leaky(q.y + nd1));
            r.z = __expf(leaky(q.z + nd2));
            r.w = __int_as_float(s);
            sl0 += r.x; sl1 += r.y; sl2 += r.z;
            pv[wv][lane] = r;
        }
#pragma unroll 8
        for (int j = 0; j < ce; ++j) {
            float4 e = pv[wv][j];              // broadcast ds_read_b128
            int s = __float_as_int(e.w);
            unsigned u = featdw[(size_t)s * 64 + lane];   // 256 B/wave, coalesced
            float lo = lo2f(u), hi = hi2f(u);
            a00 += e.x * lo; a01 += e.x * hi;
            a10 += e.y * lo; a11 += e.y * hi;
            a20 += e.z * lo; a21 += e.z * hi;
        }
    }
#pragma unroll
    for (int o = 1; o < 64; o <<= 1) {
        sl0 += __shfl_xor(sl0, o);
        sl1 += __shfl_xor(sl1, o);
        sl2 += __shfl_xor(sl2, o);
    }
    const float i0 = 1.f / sl0, i1 = 1.f / sl1, i2 = 1.f / sl2;
    outp[lane]       = packbf(a00 * i0, a01 * i0);
    outp[64 + lane]  = packbf(a10 * i1, a11 * i1);
    outp[128 + lane] = packbf(a20 * i2, a21 * i2);
}

// ---------------- fused dense chain v2: BM=32, 625 blocks -------------------
// Block = 32 rows; waves split rows x cols: rw = wv&1 (16 rows), cg = wv>>1
// (64 cols). Main GEMM aggF(32x384) @ Mcat^T (+bias,relu,resid) -> C write,
// next-layer score dots (2-partial LDS combine across cg), v-tile into lsA
// (fragx, stride 1024), then gate MLP GEMM vs p1w halves, relu.p2w reduce
// -> gpart. 42 KB LDS, 3 blocks/CU, grid 625 (2.4 blocks/CU machine fill).
__global__ __launch_bounds__(256) void fusedgemm_kernel(
    const bf16* __restrict__ A, const bf16* __restrict__ B,
    bf16* __restrict__ C, const bf16* __restrict__ bias,
    const bf16* __restrict__ resid, int do_relu,
    const bf16* __restrict__ p1w, const bf16* __restrict__ p1b,
    const bf16* __restrict__ p2w, float* __restrict__ gpart,
    const float* __restrict__ vc_next, float* __restrict__ s_next)
{
    __shared__ short lsA[4096];      // 8KB: A 32x128 panel, later v-tile
    __shared__ short lsB[16384];     // 32KB: B 128x128 panel
    __shared__ float sred[2][32][8]; // 2KB: cross-cg reduce scratch
    const int tid = threadIdx.x;
    const int wv = tid >> 6, lane = tid & 63;
    const int quad = lane >> 4, r16 = lane & 15;
    const int rw = wv & 1, cg = wv >> 1;
    const int m0 = blockIdx.x * 32;
    const short* As = (const short*)A;
    const short* Bs = (const short*)B;

    v4f acc[4];
#pragma unroll
    for (int t = 0; t < 4; ++t) acc[t] = (v4f){0.f, 0.f, 0.f, 0.f};

#pragma unroll
    for (int ks = 0; ks < 3; ++ks) {
        const int k0 = ks * 128;
        stage_panelA32(As, m0, 384, k0, lsA, tid);
        stage_panelB(Bs, 0, 384, k0, lsB, tid);
        __syncthreads();
#pragma unroll
        for (int c = 0; c < 4; ++c) {
            v8s a = fragx(lsA + c * 1024, rw * 16 + r16, quad);
#pragma unroll
            for (int t = 0; t < 4; ++t) {
                v8s b = fragx(lsB + c * 4096, cg * 64 + t * 16 + r16, quad);
                acc[t] = __builtin_amdgcn_mfma_f32_16x16x32_bf16(a, b, acc[t], 0, 0, 0);
            }
        }
        __syncthreads();   // all waves done with lsA/lsB before restage/reuse
    }

    // ---- epilogue: v = acc+bias(+relu)+resid; C write; scores; v -> lsA ----
    float bbv[4];
#pragma unroll
    for (int t = 0; t < 4; ++t)
        bbv[t] = __bfloat162float(bias[cg * 64 + t * 16 + r16]);
    float s0[4], s1[4], s2[4], s3[4], s4[4], s5[4];
#pragma unroll
    for (int reg = 0; reg < 4; ++reg) {
        s0[reg] = 0.f; s1[reg] = 0.f; s2[reg] = 0.f;
        s3[reg] = 0.f; s4[reg] = 0.f; s5[reg] = 0.f;
    }
#pragma unroll
    for (int t = 0; t < 4; ++t) {
        const int n = cg * 64 + t * 16 + r16;
        float v0 = vc_next ? vc_next[0 * 128 + n] : 0.f;
        float v1 = vc_next ? vc_next[1 * 128 + n] : 0.f;
        float v2 = vc_next ? vc_next[2 * 128 + n] : 0.f;
        float v3 = vc_next ? vc_next[3 * 128 + n] : 0.f;
        float v4 = vc_next ? vc_next[4 * 128 + n] : 0.f;
        float v5 = vc_next ? vc_next[5 * 128 + n] : 0.f;
        const int cch = n >> 5, nc = n & 31, qq = nc >> 3, e = nc & 7;
#pragma unroll
        for (int reg = 0; reg < 4; ++reg) {
            const int R = rw * 16 + quad * 4 + reg;
            const int m = m0 + R;           // always < 20000 (625*32 exact)
            float v = acc[t][reg] + bbv[t];
            if (do_relu) v = fmaxf(v, 0.f);
            v += __bfloat162float(resid[(size_t)m * 128 + n]);
            C[(size_t)m * 128 + n] = __float2bfloat16(v);
            const int pos = qq ^ ((R >> 1) & 3);
            lsA[cch * 1024 + (R * 4 + pos) * 8 + e] = (short)f2bfbits(v);
            s0[reg] += v * v0; s1[reg] += v * v1; s2[reg] += v * v2;
            s3[reg] += v * v3; s4[reg] += v * v4; s5[reg] += v * v5;
        }
    }
    if (vc_next) {
#pragma unroll
        for (int reg = 0; reg < 4; ++reg) {
#pragma unroll
            for (int o = 1; o < 16; o <<= 1) {
                s0[reg] += __shfl_xor(s0[reg], o);
                s1[reg] += __shfl_xor(s1[reg], o);
                s2[reg] += __shfl_xor(s2[reg], o);
                s3[reg] += __shfl_xor(s3[reg], o);
                s4[reg] += __shfl_xor(s4[reg], o);
                s5[reg] += __shfl_xor(s5[reg], o);
            }
            if (r16 == 0) {
                const int R = rw * 16 + quad * 4 + reg;
                sred[cg][R][0] = s0[reg]; sred[cg][R][1] = s1[reg];
                sred[cg][R][2] = s2[reg]; sred[cg][R][3] = s3[reg];
                sred[cg][R][4] = s4[reg]; sred[cg][R][5] = s5[reg];
            }
        }
    }
    __syncthreads();   // v-tile + sred complete
    if (vc_next && tid < 192) {
        const int R = tid / 6, c = tid - R * 6;
        const float sv = sred[0][R][c] + sred[1][R][c];
        s_next[(size_t)(m0 + R) * 8 + (c < 3 ? c : c + 1)] = sv;
    }

    // ---- gate MLP GEMM from lsA v-tile vs p1w halves ----
    float gacc[4] = {0.f, 0.f, 0.f, 0.f};
#pragma unroll 1
    for (int hh = 0; hh < 2; ++hh) {
        if (hh) __syncthreads();      // prev lsB reads done
        stage_panelB((const short*)p1w, hh * 128, 128, 0, lsB, tid);
        __syncthreads();
        v4f a2[4];
#pragma unroll
        for (int t = 0; t < 4; ++t) a2[t] = (v4f){0.f, 0.f, 0.f, 0.f};
#pragma unroll
        for (int c = 0; c < 4; ++c) {
            v8s a = fragx(lsA + c * 1024, rw * 16 + r16, quad);
#pragma unroll
            for (int t = 0; t < 4; ++t) {
                v8s b = fragx(lsB + c * 4096, cg * 64 + t * 16 + r16, quad);
                a2[t] = __builtin_amdgcn_mfma_f32_16x16x32_bf16(a, b, a2[t], 0, 0, 0);
            }
        }
#pragma unroll
        for (int t = 0; t < 4; ++t) {
            const int n = hh * 128 + cg * 64 + t * 16 + r16;
            float b1 = __bfloat162float(p1b[n]);
            float pw = __bfloat162float(p2w[n]);
#pragma unroll
            for (int reg = 0; reg < 4; ++reg)
                gacc[reg] += fmaxf(a2[t][reg] + b1, 0.f) * pw;
        }
    }
#pragma unroll
    for (int reg = 0; reg < 4; ++reg) {
#pragma unroll
        for (int o = 1; o < 16; o <<= 1) gacc[reg] += __shfl_xor(gacc[reg], o);
        if (r16 == 0) sred[cg][rw * 16 + quad * 4 + reg][6] = gacc[reg];
    }
    __syncthreads();
    if (tid < 32) gpart[m0 + tid] = sred[0][tid][6] + sred[1][tid][6];
}

// ---------------- standalone final pool (no fence — R20 errata) -------------
__global__ void __launch_bounds__(256) pool_acc(
    const bf16* __restrict__ feat, const float* __restrict__ gp,
    const int* __restrict__ gptr, float* __restrict__ out_acc)
{
    const int g = blockIdx.x;
    const int chunk = blockIdx.y;
    const int tid = threadIdx.x;
    const int beg = gptr[g], end = gptr[g + 1];
    if (beg >= end) return;
    __shared__ float red[4];
    float m = -1e30f;
    for (int i = beg + tid; i < end; i += 256)
        m = fmaxf(m, gp[i]);
#pragma unroll
    for (int o = 32; o > 0; o >>= 1) m = fmaxf(m, __shfl_xor(m, o));
    if ((tid & 63) == 0) red[tid >> 6] = m;
    __syncthreads();
    m = fmaxf(fmaxf(red[0], red[1]), fmaxf(red[2], red[3]));
    __syncthreads();
    float s = 0.f;
    for (int i = beg + tid; i < end; i += 256)
        s += __expf(gp[i] - m);
#pragma unroll
    for (int o = 32; o > 0; o >>= 1) s += __shfl_xor(s, o);
    if ((tid & 63) == 0) red[tid >> 6] = s;
    __syncthreads();
    float inv = 1.f / (red[0] + red[1] + red[2] + red[3]);
    const int p = tid >> 7;
    const int c = tid & 127;
    float acc = 0.f;
    for (int i = beg + chunk * 2 + p; i < end; i += 16) {
        float w = __expf(gp[i] - m);
        acc += w * __bfloat162float(feat[(size_t)i * DIM + c]);
    }
    acc *= inv;
    atomicAdd(&out_acc[g * DIM + c], acc);
}

__global__ void writeout_kernel(const float* __restrict__ out_acc,
                                void* __restrict__ out, const int* __restrict__ flag) {
    int i = blockIdx.x * 256 + threadIdx.x;
    if (i < NGRAPH * DIM) {
        float v = out_acc[i] * (1.f / 3.f);
        if ((*flag) > 8) ((float*)out)[i] = v;
        else ((bf16*)out)[i] = __float2bfloat16(v);
    }
}

// ---------------- host launcher ----------------
extern "C" void kernel_launch(void* const* d_in, const int* in_sizes, int n_in,
                              void* d_out, int out_size, void* d_ws, size_t ws_size,
                              hipStream_t stream)
{
    const void* feat_in = d_in[0];
    const int* src = (const int*)d_in[1];
    const int* dst = (const int*)d_in[2];
    const int* gid = (const int*)d_in[3];

    char* base = (char*)d_ws;
    size_t off = 0;
    auto carve = [&](size_t bytes) -> void* {
        void* p = base + off;
        off = (off + bytes + 255) & ~(size_t)255;
        return p;
    };
    int* dflag = (int*)carve(256);   // NOT zeroed; init block 0 stores it
    size_t zbytes = sizeof(int) * 2 * N_NODES + sizeof(float) * NGRAPH * DIM;
    char* zreg  = (char*)carve(zbytes);
    int* deg    = (int*)zreg;
    int* cursor = deg + N_NODES;
    float* out_acc = (float*)(cursor + N_NODES);
    float* gpart3 = (float*)carve(sizeof(float) * LAYERS * N_NODES);
    int* rp     = (int*)carve(sizeof(int) * (N_NODES + 1));
    int* gptr   = (int*)carve(sizeof(int) * (NGRAPH + 1));
    int* esrc   = (int*)carve(sizeof(int) * N_EDGES);
    float* s_bufA = (float*)carve(sizeof(float) * N_NODES * 8);
    float* s_bufB = (float*)carve(sizeof(float) * N_NODES * 8);
    float* vcat = (float*)carve(sizeof(float) * LAYERS * 6 * 128);
    bf16* mcat  = (bf16*)carve(sizeof(bf16) * LAYERS * 128 * 384);
    bf16* featA = (bf16*)carve(sizeof(bf16) * N_NODES * DIM);
    bf16* featB = (bf16*)carve(sizeof(bf16) * N_NODES * DIM);
    bf16* cfc   = (bf16*)carve(sizeof(bf16) * LAYERS * HEADS * DIM * DIM);
    bf16* cans  = (bf16*)carve(sizeof(bf16) * LAYERS * HEADS * DIM);
    bf16* cand  = (bf16*)carve(sizeof(bf16) * LAYERS * HEADS * DIM);
    bf16* ctw   = (bf16*)carve(sizeof(bf16) * LAYERS * DIM * HEADS * DIM);
    bf16* ctb   = (bf16*)carve(sizeof(bf16) * LAYERS * DIM);
    bf16* cp1w  = (bf16*)carve(sizeof(bf16) * LAYERS * 2 * DIM * DIM);
    bf16* cp1b  = (bf16*)carve(sizeof(bf16) * LAYERS * 2 * DIM);
    bf16* cp2w  = (bf16*)carve(sizeof(bf16) * LAYERS * 2 * DIM);
    bf16* aggF  = (bf16*)carve(sizeof(bf16) * N_NODES * HEADS * DIM);
    carve(131072);   // pad: GEMM A-tile tail overreads

    if (off > ws_size) {
        sentinel_kernel<<<(out_size + 255) / 256, 256, 0, stream>>>(
            (bf16*)d_out, out_size);
        return;
    }

    init_kernel<<<128, 256, 0, stream>>>(
        (unsigned*)zreg, (int)(zbytes / 4), (const unsigned short*)feat_in, dflag);

    CvtArgs ca;
    const int cvt_n[NCVT] = {
        N_NODES * DIM, LAYERS * HEADS * DIM * DIM, LAYERS * HEADS * DIM,
        LAYERS * HEADS * DIM, LAYERS * DIM * HEADS * DIM, LAYERS * DIM,
        LAYERS * 2 * DIM * DIM, LAYERS * 2 * DIM, LAYERS * 2 * DIM };
    bf16* cvt_dst[NCVT] = { featA, cfc, cans, cand, ctw, ctb, cp1w, cp1b, cp2w };
    const int cvt_src_idx[NCVT] = { 0, 4, 5, 6, 7, 8, 9, 10, 11 };
    int total4 = 0;
    for (int s = 0; s < NCVT; ++s) {
        ca.src[s] = d_in[cvt_src_idx[s]];
        ca.dst[s] = cvt_dst[s];
        ca.n[s] = cvt_n[s];
        ca.n4[s] = (cvt_n[s] + 3) / 4;
        total4 += ca.n4[s];
    }
    const int cvtBlocks = (total4 + 255) / 256;
    const int cntBlocks = (N_EDGES + 255) / 256;
    cvtcount_kernel<<<cvtBlocks + cntBlocks, 256, 0, stream>>>(
        ca, dflag, dst, deg, cvtBlocks);

    scanprep_kernel<<<LAYERS * 25 + 1, 256, 0, stream>>>(
        deg, rp, gid, gptr, cfc, cans, cand, ctw, mcat, vcat);

    bf16* fin = featA;
    bf16* fout = featB;
    for (int d = 0; d < LAYERS; ++d) {
        float* s_cur = (d & 1) ? s_bufB : s_bufA;
        float* s_next = (d & 1) ? s_bufA : s_bufB;
        if (d == 0) {
            fillscore_kernel<<<cntBlocks + NODE_BLOCKS, 256, 0, stream>>>(
                fin, vcat, s_cur, src, dst, rp, cursor, esrc, cntBlocks);
        }
        const int poolBlocks = (d == 0) ? 0 : NGRAPH * 8;
        aggpool_kernel<<<poolBlocks + (N_NODES + 3) / 4, 256, 0, stream>>>(
            (const unsigned*)fin, rp, esrc, s_cur, aggF,
            (d == 0) ? nullptr : gpart3 + (size_t)(d - 1) * N_NODES,
            gptr, out_acc, poolBlocks);
        fusedgemm_kernel<<<NBLK32, 256, 0, stream>>>(
            aggF, mcat + (size_t)d * 128 * 384, fout,
            ctb + (size_t)d * DIM, fin, (d < LAYERS - 1) ? 1 : 0,
            cp1w + (size_t)d * 2 * DIM * DIM, cp1b + (size_t)d * 2 * DIM,
            cp2w + (size_t)d * 2 * DIM, gpart3 + (size_t)d * N_NODES,
            (d < LAYERS - 1) ? vcat + (size_t)(d + 1) * 6 * 128 : nullptr,
            s_next);
        bf16* t = fin; fin = fout; fout = t;
    }
    pool_acc<<<dim3(NGRAPH, 8), 256, 0, stream>>>(
        fin, gpart3 + (size_t)2 * N_NODES, gptr, out_acc);
    writeout_kernel<<<(NGRAPH * DIM + 255) / 256, 256, 0, stream>>>(
        out_acc, d_out, dflag);
}